// Round 3
// baseline (3255.186 us; speedup 1.0000x reference)
//
#include <hip/hip_runtime.h>
#include <cstdint>

typedef unsigned short u16;
typedef __attribute__((ext_vector_type(8))) short s16x8;    // 8 bf16 (4 VGPRs)
typedef __attribute__((ext_vector_type(4))) float f32x4;    // 16x16 MFMA C/D frag
typedef __attribute__((ext_vector_type(16))) float f32x16;  // 32x32 MFMA C/D frag

#define T_LEN 256
#define BATCH 64
#define HID   1024
#define NWG   64
#define GLD   68     // Gbuf leading dim (f32): 16B-aligned b128 reads, uniform banks

// ---------- bf16 helpers ----------
__device__ __forceinline__ float b2f(u16 u) {
    union { unsigned u; float f; } v; v.u = ((unsigned)u) << 16; return v.f;
}
__device__ __forceinline__ u16 f2b(float f) {
    union { float f; unsigned u; } v; v.f = f;
    unsigned u = v.u;
    return (u16)((u + 0x7fffu + ((u >> 16) & 1u)) >> 16);
}
__device__ __forceinline__ float sigmoidf_(float x) { return 1.0f / (1.0f + __expf(-x)); }
__device__ __forceinline__ float tanhf_(float x) {
    float e = __expf(2.0f * x);
    return 1.0f - 2.0f / (e + 1.0f);
}

// ---------- fp32 -> bf16 bulk convert ----------
__global__ __launch_bounds__(256) void f32_to_bf16(const float4* __restrict__ in,
                                                   ushort4* __restrict__ out, int n4) {
    int i = blockIdx.x * 256 + threadIdx.x;
    if (i < n4) {
        float4 v = in[i];
        ushort4 o;
        o.x = f2b(v.x); o.y = f2b(v.y); o.z = f2b(v.z); o.w = f2b(v.w);
        out[i] = o;
    }
}

// ---------- transpose 1024x1024: out_bf16[c][r] = (bf16)in_f32[r][c] ----------
__global__ __launch_bounds__(256) void transpose_f32_bf16(const float* __restrict__ in,
                                                          u16* __restrict__ out) {
    __shared__ u16 tile[64][65];
    int tx = threadIdx.x & 63, ty = threadIdx.x >> 6;
    int r0 = blockIdx.y * 64, c0 = blockIdx.x * 64;
    for (int r = ty; r < 64; r += 4)
        tile[r][tx] = f2b(in[(size_t)(r0 + r) * 1024 + c0 + tx]);
    __syncthreads();
    for (int c = ty; c < 64; c += 4)
        out[(size_t)(c0 + c) * 1024 + r0 + tx] = tile[tx][c];
}

// ---------- init: counters, fused bias, HsBuf[0] = (bf16)H0 in Hp layout ----------
// Hp layout per step-chunk (65536 u16): off(b,k) = (k>>4)*1024 + b*16 + (k&15)
__global__ __launch_bounds__(256) void init_misc(const float* __restrict__ H0,
                                                 u16* __restrict__ HsBuf,
                                                 unsigned* __restrict__ cnt,
                                                 const float* __restrict__ b_i,
                                                 const float* __restrict__ b_f,
                                                 const float* __restrict__ b_o,
                                                 const float* __restrict__ b_c,
                                                 float* __restrict__ fbias) {
    int i = blockIdx.x * 256 + threadIdx.x;   // grid 256x256 = 65536
    if (i < 1024) cnt[i] = 0u;
    if (i < 4096) {
        int g = i >> 10, k = i & 1023;
        const float* bp = (g == 0) ? b_i : (g == 1) ? b_f : (g == 2) ? b_o : b_c;
        fbias[i] = bp[k];
    }
    if (i < BATCH * HID) {
        int b = i >> 10, k = i & 1023;
        HsBuf[(size_t)(k >> 4) * 1024 + b * 16 + (k & 15)] = f2b(H0[i]);
    }
}

// ---------- pack W_h (4 mats, [h][k] transposed layout) into MFMA-frag order ----
__global__ __launch_bounds__(256) void pack_wh(const u16* __restrict__ WThT,
                                               u16* __restrict__ Wpack) {
    size_t idx = (size_t)blockIdx.x * 256 + threadIdx.x;  // 0..524287
    int lane = idx & 63;
    int kc   = (idx >> 6) & 63;
    int ct   = (idx >> 12) & 1;
    int j    = (int)(idx >> 13);
    int ln = lane & 31, kh = lane >> 5;
    int col = ct * 32 + ln;
    int g = col >> 4, hi = col & 15;
    const uint4* src = (const uint4*)(WThT + (size_t)g * 1048576 +
                                      (size_t)(16 * j + hi) * 1024 + kc * 16 + kh * 8);
    ((uint4*)Wpack)[idx] = *src;
}

// ---------- GEMM: C[m][col] = A[m][:] . BT[col][:] + bias[col] ----------
// mode 0: Cf fp32 row-major [M][ldc].  mode 1: Cb bf16 permuted X layout (g fastest)
//   off(t,b,g,h) = t*262144 + (h>>4)*4096 + b*64 + (h&15)*4 + g, row=t*64+b, col=g*1024+h
// aperm: A is in Hp layout (per-64-row chunk of 65536 u16, off = (k>>4)*1024 + b*16 + (k&15))
__global__ __launch_bounds__(256) void gemm_bt(const u16* __restrict__ A,
                                               const u16* __restrict__ BT,
                                               const float* __restrict__ bias,
                                               u16* __restrict__ Cb,
                                               float* __restrict__ Cf,
                                               int M, int K, int ldc, int xperm, int aperm) {
    __shared__ __align__(16) u16 As[128 * 32];
    __shared__ __align__(16) u16 Bs[128 * 32];
    const int tid  = threadIdx.x;
    const int lane = tid & 63;
    const int w    = tid >> 6;
    const int wm   = (w >> 1) * 64;
    const int wn   = (w & 1) * 64;
    const long m0 = (long)blockIdx.x * 128;
    const long n0 = (long)blockIdx.y * 128;
    const int lrow = lane & 15;
    const int lq   = lane >> 4;

    f32x4 acc[4][4];
    const f32x4 vzero = {0.f, 0.f, 0.f, 0.f};
    #pragma unroll
    for (int i = 0; i < 4; ++i)
        #pragma unroll
        for (int j = 0; j < 4; ++j) acc[i][j] = vzero;

    for (int k0 = 0; k0 < K; k0 += 32) {
        __syncthreads();
        #pragma unroll
        for (int i = 0; i < 2; ++i) {
            int chunk = i * 256 + w * 64 + lane;
            const u16* ga;
            if (aperm) {
                long row = m0 + (chunk >> 2);
                int  c   = chunk & 3;
                ga = A + (row >> 6) * 65536L + (long)((k0 >> 4) + (c >> 1)) * 1024 +
                     (row & 63) * 16 + (c & 1) * 8;
            } else {
                ga = A + (m0 + (chunk >> 2)) * (long)K + k0 + (chunk & 3) * 8;
            }
            __builtin_amdgcn_global_load_lds(
                (const __attribute__((address_space(1))) unsigned int*)ga,
                (__attribute__((address_space(3))) unsigned int*)(As + (i * 256 + w * 64) * 8),
                16, 0, 0);
            const u16* gb = BT + (n0 + (chunk >> 2)) * (long)K + k0 + (chunk & 3) * 8;
            __builtin_amdgcn_global_load_lds(
                (const __attribute__((address_space(1))) unsigned int*)gb,
                (__attribute__((address_space(3))) unsigned int*)(Bs + (i * 256 + w * 64) * 8),
                16, 0, 0);
        }
        __syncthreads();
        s16x8 af[4], bf[4];
        #pragma unroll
        for (int i = 0; i < 4; ++i)
            af[i] = *(const s16x8*)(As + (wm + i * 16 + lrow) * 32 + lq * 8);
        #pragma unroll
        for (int j = 0; j < 4; ++j)
            bf[j] = *(const s16x8*)(Bs + (wn + j * 16 + lrow) * 32 + lq * 8);
        #pragma unroll
        for (int i = 0; i < 4; ++i)
            #pragma unroll
            for (int j = 0; j < 4; ++j)
                acc[i][j] = __builtin_amdgcn_mfma_f32_16x16x32_bf16(af[i], bf[j], acc[i][j], 0, 0, 0);
    }
    #pragma unroll
    for (int j = 0; j < 4; ++j) {
        long col = n0 + wn + j * 16 + lrow;
        float bv = bias[col];
        #pragma unroll
        for (int i = 0; i < 4; ++i) {
            long rowb = m0 + wm + i * 16 + lq * 4;
            #pragma unroll
            for (int r = 0; r < 4; ++r) {
                float v = acc[i][j][r] + bv;
                long row = rowb + r;
                if (xperm) {
                    long t = row >> 6, b = row & 63;
                    long g = col >> 10, h = col & 1023;
                    Cb[t * 262144 + (h >> 4) * 4096 + b * 64 + (h & 15) * 4 + g] = f2b(v);
                } else {
                    Cf[row * (long)ldc + col] = v;
                }
            }
        }
    }
}

// ---------- persistent LSTM recurrence: 64 WGs, 1 barrier/step ----------
// WG j owns cols c = g*16+hi (4 gates x 16 h), h = 16j+hi.
// Wave (bt,ct): 32 b-rows x 32 cols, 32x32x16 MFMA, W frags lane-linear in LDS.
// H lives in Hp layout [t][k>>4][b][k&15]:
//   - A-frag loads are wave-contiguous 1 KB bursts
//   - H stores: one dwordx2 per thread, 512 B contiguous per wave-instr
// Barrier: per-WG leaf add (8 leaves); wave-0 lanes poll all 8 leaves directly
// (no root hop). Coherence: write-through H stores (sc0 sc1).
// No L2 warming: co-XCD CUs' concurrent A-streams dedupe in L2 MSHRs.
// X prefetched one step ahead (HBM latency hides under drain+barrier).
__global__ __launch_bounds__(256, 1) void lstm_steps(const u16* __restrict__ Xp,
                                                     const u16* __restrict__ Wpack,
                                                     const float* __restrict__ C0,
                                                     u16* __restrict__ HsBuf,
                                                     float* __restrict__ out,
                                                     unsigned* __restrict__ cnt) {
    extern __shared__ char smem[];
    u16*   Wlds = (u16*)smem;                 // 131072 B, frag-packed
    float* Gbuf = (float*)(smem + 131072);    // 64*68*4 = 17408 B
    const int tid  = threadIdx.x;
    const int lane = tid & 63;
    const int w    = tid >> 6;
    const int j    = blockIdx.x;
    const int ln   = lane & 31;
    const int kh   = lane >> 5;
    const int bt   = w >> 1;
    const int ct   = w & 1;

    {   // stage packed W slice (128 KB contiguous, coalesced)
        const uint4* wsrc = (const uint4*)Wpack + (size_t)j * 8192;
        uint4* wdst = (uint4*)Wlds;
        for (int i = tid; i < 8192; i += 256) wdst[i] = wsrc[i];
    }

    // pointwise mapping: thread -> (batch row pb, 4 consecutive h at 16j+hq)
    const int pb = tid >> 2;
    const int hq = (tid & 3) * 4;
    f32x4 c_reg = *(const f32x4*)(C0 + (size_t)pb * 1024 + 16 * j + hq);

    __syncthreads();

    unsigned* leaf = cnt + (j & 7) * 32;   // 8 leaves, 128 B apart
    const u16* wbase = Wlds + ct * 32768 + lane * 8;

    // X prefetch for t=0 (layout: [t][j][b][(h&15)][g], g fastest)
    s16x8 xlo, xhi;
    {
        const u16* xb0 = Xp + (size_t)j * 4096 + (size_t)pb * 64 + (size_t)hq * 4;
        xlo = *(const s16x8*)(xb0);
        xhi = *(const s16x8*)(xb0 + 8);
    }

    for (int t = 0; t < T_LEN; ++t) {
        const u16* Hbase = HsBuf + (size_t)t * 65536;

        // --- MFMA: G = H_t @ W slice; A-loads wave-contiguous 1 KB (Hp layout) ---
        const u16* hrow = Hbase + (size_t)(bt * 32 + ln) * 16 + kh * 8;
        f32x16 acc0 = {};
        f32x16 acc1 = {};
        #pragma unroll 8
        for (int kc = 0; kc < 64; kc += 2) {
            s16x8 a0 = *(const s16x8*)(hrow + (size_t)kc * 1024);
            s16x8 a1 = *(const s16x8*)(hrow + (size_t)kc * 1024 + 1024);
            s16x8 b0 = *(const s16x8*)(wbase + kc * 512);
            s16x8 b1 = *(const s16x8*)(wbase + kc * 512 + 512);
            acc0 = __builtin_amdgcn_mfma_f32_32x32x16_bf16(a0, b0, acc0, 0, 0, 0);
            acc1 = __builtin_amdgcn_mfma_f32_32x32x16_bf16(a1, b1, acc1, 0, 0, 0);
        }
        // C/D layout 32x32: col = lane&31, row = (reg&3) + 8*(reg>>2) + 4*(lane>>5)
        #pragma unroll
        for (int r = 0; r < 16; ++r) {
            int row = bt * 32 + (r & 3) + 8 * (r >> 2) + 4 * kh;
            Gbuf[row * GLD + ct * 32 + ln] = acc0[r] + acc1[r];
        }
        __syncthreads();

        // --- pointwise: vector Gbuf reads, 1 dwordx2 write-through H store ---
        const float* gp = Gbuf + pb * GLD + hq;
        f32x4 gI = *(const f32x4*)(gp);
        f32x4 gF = *(const f32x4*)(gp + 16);
        f32x4 gO = *(const f32x4*)(gp + 32);
        f32x4 gC = *(const f32x4*)(gp + 48);
        unsigned long long hv = 0ull;
        f32x4 hnv;
        #pragma unroll
        for (int i = 0; i < 4; ++i) {
            s16x8 xv = (i < 2) ? xlo : xhi;
            int base = (i & 1) * 4;
            float I  = sigmoidf_(gI[i] + b2f((u16)xv[base + 0]));
            float F  = sigmoidf_(gF[i] + b2f((u16)xv[base + 1]));
            float O  = sigmoidf_(gO[i] + b2f((u16)xv[base + 2]));
            float Ct = tanhf_   (gC[i] + b2f((u16)xv[base + 3]));
            float cn = F * c_reg[i] + I * Ct;
            c_reg[i] = cn;
            float hn = O * tanhf_(cn);
            hnv[i] = hn;
            hv |= (unsigned long long)f2b(hn) << (16 * i);
        }

        // --- prefetch next-step X (HBM latency hides under drain + barrier) ---
        if (t + 1 < T_LEN) {
            const u16* xbn = Xp + (size_t)(t + 1) * 262144 + (size_t)j * 4096 +
                             (size_t)pb * 64 + (size_t)hq * 4;
            xlo = *(const s16x8*)(xbn);
            xhi = *(const s16x8*)(xbn + 8);
        }

        // --- write-through H store: 8 B/thread, 512 B contiguous per wave ---
        u16* dst = HsBuf + (size_t)(t + 1) * 65536 + (size_t)j * 1024 + pb * 16 + hq;
        asm volatile("global_store_dwordx2 %0, %1, off sc0 sc1"
                     :: "v"(dst), "v"(hv) : "memory");

        if (t == T_LEN - 1) {
            *(float4*)(out + 16777216 + (size_t)pb * 1024 + 16 * j + hq) = *(float4*)&hnv;     // Hf
            *(float4*)(out + 16777216 + 65536 + (size_t)pb * 1024 + 16 * j + hq) = *(float4*)&c_reg; // Cf
            break;
        }

        // release: drain asm stores, sync waves, leaf add; acquire: poll 8 leaves
        asm volatile("s_waitcnt vmcnt(0)" ::: "memory");
        __syncthreads();
        if (tid == 0)
            __hip_atomic_fetch_add(leaf, 1u, __ATOMIC_RELAXED, __HIP_MEMORY_SCOPE_AGENT);
        if (w == 0) {
            unsigned tgt = 8u * (unsigned)(t + 1);
            const unsigned* lp = cnt + (lane & 7) * 32;
            while (__hip_atomic_load(lp, __ATOMIC_RELAXED, __HIP_MEMORY_SCOPE_AGENT) < tgt)
                __builtin_amdgcn_s_sleep(2);
        }
        __syncthreads();
    }
}

// ---------- workspace layout (bytes) ----------
//   0         : cnt[1024] (8 leaves at dword (j&7)*32)                    4096 B
//   4096      : fused bias f32[4096]                                     16384 B
//   20480     : 9 transposed bf16 weights, 2 MB each (Wxi..Wxc, Whi..Whc, Whq)
//   18894848  : Wpack bf16, MFMA-frag order                            8388608 B
//   27283456  : Xbf  bf16 [16384][1024]                               33554432 B
//   60837888  : Xp   bf16 permuted [t][h>>4][b][h&15][g]             134217728 B
//   195055616 : HsBuf bf16 [257] chunks, Hp layout [k>>4][b][k&15]    33685504 B
extern "C" void kernel_launch(void* const* d_in, const int* in_sizes, int n_in,
                              void* d_out, int out_size, void* d_ws, size_t ws_size,
                              hipStream_t stream) {
    const float* inputs = (const float*)d_in[0];
    const float* H0   = (const float*)d_in[1];
    const float* C0   = (const float*)d_in[2];
    const float* W_xi = (const float*)d_in[3];
    const float* W_hi = (const float*)d_in[4];
    const float* b_i  = (const float*)d_in[5];
    const float* W_xf = (const float*)d_in[6];
    const float* W_hf = (const float*)d_in[7];
    const float* b_f  = (const float*)d_in[8];
    const float* W_xo = (const float*)d_in[9];
    const float* W_ho = (const float*)d_in[10];
    const float* b_o  = (const float*)d_in[11];
    const float* W_xc = (const float*)d_in[12];
    const float* W_hc = (const float*)d_in[13];
    const float* b_c  = (const float*)d_in[14];
    const float* W_hq = (const float*)d_in[15];
    const float* b_q  = (const float*)d_in[16];

    float* out = (float*)d_out;
    char* ws = (char*)d_ws;
    unsigned* cnt  = (unsigned*)ws;
    float* fbias   = (float*)(ws + 4096);
    u16* WT        = (u16*)(ws + 20480);
    u16* Wpack     = (u16*)(ws + 18894848);
    u16* Xbf       = (u16*)(ws + 27283456);
    u16* Xp        = (u16*)(ws + 60837888);
    u16* HsBuf     = (u16*)(ws + 195055616);

    f32_to_bf16<<<16384, 256, 0, stream>>>((const float4*)inputs, (ushort4*)Xbf, 4194304);

    const float* wsrcs[9] = {W_xi, W_xf, W_xo, W_xc, W_hi, W_hf, W_ho, W_hc, W_hq};
    for (int i = 0; i < 9; ++i)
        transpose_f32_bf16<<<dim3(16, 16), 256, 0, stream>>>(wsrcs[i], WT + (size_t)i * 1048576);

    init_misc<<<256, 256, 0, stream>>>(H0, HsBuf, cnt, b_i, b_f, b_o, b_c, fbias);
    pack_wh<<<2048, 256, 0, stream>>>(WT + (size_t)4 * 1048576, Wpack);

    // fused input projection -> permuted X layout
    gemm_bt<<<dim3(128, 32), 256, 0, stream>>>(Xbf, WT, fbias, Xp, (float*)nullptr,
                                               16384, 1024, 4096, 1, 0);

    (void)hipFuncSetAttribute((const void*)lstm_steps,
                              hipFuncAttributeMaxDynamicSharedMemorySize, 148480);
    lstm_steps<<<NWG, 256, 148480, stream>>>(Xp, Wpack, C0, HsBuf, out, cnt);

    // outputs = Hs @ W_hq + b_q (fp32 out), A in Hp layout
    gemm_bt<<<dim3(128, 8), 256, 0, stream>>>(HsBuf + 65536, WT + (size_t)8 * 1048576, b_q,
                                              (u16*)nullptr, out, 16384, 1024, 1024, 0, 1);
}

// Round 4
// 2725.919 us; speedup vs baseline: 1.1942x; 1.1942x over previous
//
#include <hip/hip_runtime.h>
#include <cstdint>

typedef unsigned short u16;
typedef __attribute__((ext_vector_type(8))) short s16x8;    // 8 bf16 (4 VGPRs)
typedef __attribute__((ext_vector_type(4))) float f32x4;    // 16x16 MFMA C/D frag
typedef __attribute__((ext_vector_type(16))) float f32x16;  // 32x32 MFMA C/D frag

#define T_LEN 256
#define BATCH 64
#define HID   1024
#define NWG   64
#define GLD   68     // Gbuf leading dim (f32): 16B-aligned b128 reads

// ---------- bf16 helpers ----------
__device__ __forceinline__ float b2f(u16 u) {
    union { unsigned u; float f; } v; v.u = ((unsigned)u) << 16; return v.f;
}
__device__ __forceinline__ u16 f2b(float f) {
    union { float f; unsigned u; } v; v.f = f;
    unsigned u = v.u;
    return (u16)((u + 0x7fffu + ((u >> 16) & 1u)) >> 16);
}
__device__ __forceinline__ float sigmoidf_(float x) { return 1.0f / (1.0f + __expf(-x)); }
__device__ __forceinline__ float tanhf_(float x) {
    float e = __expf(2.0f * x);
    return 1.0f - 2.0f / (e + 1.0f);
}

// ---------- fp32 -> bf16 bulk convert ----------
__global__ __launch_bounds__(256) void f32_to_bf16(const float4* __restrict__ in,
                                                   ushort4* __restrict__ out, int n4) {
    int i = blockIdx.x * 256 + threadIdx.x;
    if (i < n4) {
        float4 v = in[i];
        ushort4 o;
        o.x = f2b(v.x); o.y = f2b(v.y); o.z = f2b(v.z); o.w = f2b(v.w);
        out[i] = o;
    }
}

// ---------- transpose 1024x1024: out_bf16[c][r] = (bf16)in_f32[r][c] ----------
__global__ __launch_bounds__(256) void transpose_f32_bf16(const float* __restrict__ in,
                                                          u16* __restrict__ out) {
    __shared__ u16 tile[64][65];
    int tx = threadIdx.x & 63, ty = threadIdx.x >> 6;
    int r0 = blockIdx.y * 64, c0 = blockIdx.x * 64;
    for (int r = ty; r < 64; r += 4)
        tile[r][tx] = f2b(in[(size_t)(r0 + r) * 1024 + c0 + tx]);
    __syncthreads();
    for (int c = ty; c < 64; c += 4)
        out[(size_t)(c0 + c) * 1024 + r0 + tx] = tile[tx][c];
}

// ---------- init: counters, fused bias, HsBuf[0] = (bf16)H0 in Hp layout ----------
// Hp layout per step-chunk (65536 u16): off(b,k) = (k>>4)*1024 + b*16 + (k&15)
__global__ __launch_bounds__(256) void init_misc(const float* __restrict__ H0,
                                                 u16* __restrict__ HsBuf,
                                                 unsigned* __restrict__ cnt,
                                                 const float* __restrict__ b_i,
                                                 const float* __restrict__ b_f,
                                                 const float* __restrict__ b_o,
                                                 const float* __restrict__ b_c,
                                                 float* __restrict__ fbias) {
    int i = blockIdx.x * 256 + threadIdx.x;   // grid 256x256 = 65536
    if (i < 1024) cnt[i] = 0u;
    if (i < 4096) {
        int g = i >> 10, k = i & 1023;
        const float* bp = (g == 0) ? b_i : (g == 1) ? b_f : (g == 2) ? b_o : b_c;
        fbias[i] = bp[k];
    }
    if (i < BATCH * HID) {
        int b = i >> 10, k = i & 1023;
        HsBuf[(size_t)(k >> 4) * 1024 + b * 16 + (k & 15)] = f2b(H0[i]);
    }
}

// ---------- pack W_h (4 mats, [h][k] transposed layout) into MFMA-frag order ----
__global__ __launch_bounds__(256) void pack_wh(const u16* __restrict__ WThT,
                                               u16* __restrict__ Wpack) {
    size_t idx = (size_t)blockIdx.x * 256 + threadIdx.x;  // 0..524287
    int lane = idx & 63;
    int kc   = (idx >> 6) & 63;
    int ct   = (idx >> 12) & 1;
    int j    = (int)(idx >> 13);
    int ln = lane & 31, kh = lane >> 5;
    int col = ct * 32 + ln;
    int g = col >> 4, hi = col & 15;
    const uint4* src = (const uint4*)(WThT + (size_t)g * 1048576 +
                                      (size_t)(16 * j + hi) * 1024 + kc * 16 + kh * 8);
    ((uint4*)Wpack)[idx] = *src;
}

// ---------- GEMM: C[m][col] = A[m][:] . BT[col][:] + bias[col] ----------
// mode 0: Cf fp32 row-major [M][ldc].  mode 1: Cb bf16 permuted X layout (g fastest)
//   off(t,b,g,h) = t*262144 + (h>>4)*4096 + b*64 + (h&15)*4 + g, row=t*64+b, col=g*1024+h
// aperm: A is in Hp layout (per-64-row chunk of 65536 u16, off = (k>>4)*1024 + b*16 + (k&15))
__global__ __launch_bounds__(256) void gemm_bt(const u16* __restrict__ A,
                                               const u16* __restrict__ BT,
                                               const float* __restrict__ bias,
                                               u16* __restrict__ Cb,
                                               float* __restrict__ Cf,
                                               int M, int K, int ldc, int xperm, int aperm) {
    __shared__ __align__(16) u16 As[128 * 32];
    __shared__ __align__(16) u16 Bs[128 * 32];
    const int tid  = threadIdx.x;
    const int lane = tid & 63;
    const int w    = tid >> 6;
    const int wm   = (w >> 1) * 64;
    const int wn   = (w & 1) * 64;
    const long m0 = (long)blockIdx.x * 128;
    const long n0 = (long)blockIdx.y * 128;
    const int lrow = lane & 15;
    const int lq   = lane >> 4;

    f32x4 acc[4][4];
    const f32x4 vzero = {0.f, 0.f, 0.f, 0.f};
    #pragma unroll
    for (int i = 0; i < 4; ++i)
        #pragma unroll
        for (int j = 0; j < 4; ++j) acc[i][j] = vzero;

    for (int k0 = 0; k0 < K; k0 += 32) {
        __syncthreads();
        #pragma unroll
        for (int i = 0; i < 2; ++i) {
            int chunk = i * 256 + w * 64 + lane;
            const u16* ga;
            if (aperm) {
                long row = m0 + (chunk >> 2);
                int  c   = chunk & 3;
                ga = A + (row >> 6) * 65536L + (long)((k0 >> 4) + (c >> 1)) * 1024 +
                     (row & 63) * 16 + (c & 1) * 8;
            } else {
                ga = A + (m0 + (chunk >> 2)) * (long)K + k0 + (chunk & 3) * 8;
            }
            __builtin_amdgcn_global_load_lds(
                (const __attribute__((address_space(1))) unsigned int*)ga,
                (__attribute__((address_space(3))) unsigned int*)(As + (i * 256 + w * 64) * 8),
                16, 0, 0);
            const u16* gb = BT + (n0 + (chunk >> 2)) * (long)K + k0 + (chunk & 3) * 8;
            __builtin_amdgcn_global_load_lds(
                (const __attribute__((address_space(1))) unsigned int*)gb,
                (__attribute__((address_space(3))) unsigned int*)(Bs + (i * 256 + w * 64) * 8),
                16, 0, 0);
        }
        __syncthreads();
        s16x8 af[4], bf[4];
        #pragma unroll
        for (int i = 0; i < 4; ++i)
            af[i] = *(const s16x8*)(As + (wm + i * 16 + lrow) * 32 + lq * 8);
        #pragma unroll
        for (int j = 0; j < 4; ++j)
            bf[j] = *(const s16x8*)(Bs + (wn + j * 16 + lrow) * 32 + lq * 8);
        #pragma unroll
        for (int i = 0; i < 4; ++i)
            #pragma unroll
            for (int j = 0; j < 4; ++j)
                acc[i][j] = __builtin_amdgcn_mfma_f32_16x16x32_bf16(af[i], bf[j], acc[i][j], 0, 0, 0);
    }
    #pragma unroll
    for (int j = 0; j < 4; ++j) {
        long col = n0 + wn + j * 16 + lrow;
        float bv = bias[col];
        #pragma unroll
        for (int i = 0; i < 4; ++i) {
            long rowb = m0 + wm + i * 16 + lq * 4;
            #pragma unroll
            for (int r = 0; r < 4; ++r) {
                float v = acc[i][j][r] + bv;
                long row = rowb + r;
                if (xperm) {
                    long t = row >> 6, b = row & 63;
                    long g = col >> 10, h = col & 1023;
                    Cb[t * 262144 + (h >> 4) * 4096 + b * 64 + (h & 15) * 4 + g] = f2b(v);
                } else {
                    Cf[row * (long)ldc + col] = v;
                }
            }
        }
    }
}

// ---------- persistent LSTM recurrence: 64 WGs, 1 barrier/step ----------
// WG j owns cols c = g*16+hi (4 gates x 16 h), h = 16j+hi.
// Wave (bt,ct): 32 b-rows x 32 cols, 32x32x16 MFMA, W frags lane-linear in LDS.
// H lives in Hp layout [t][k>>4][b][k&15]:
//   - A-frag loads are wave-contiguous 1 KB bursts
//   - H stores: one dwordx2 per thread, 512 B contiguous per wave-instr
// L2 warming (PROVEN, round 3 ablated it and lost 2.7 us/step): 8 co-XCD WGs
// each stream 1/8 of H_t into Gbuf-scratch so MFMA A-loads hit warm XCD-L2
// instead of serializing on MALL round-trips.
// Barrier: leaf+root two-level (round-2 proven). Coherence: write-through
// H stores (sc0 sc1); NO per-step cache maintenance.
// X prefetched one step ahead (HBM latency hides under drain+barrier).
__global__ __launch_bounds__(256, 1) void lstm_steps(const u16* __restrict__ Xp,
                                                     const u16* __restrict__ Wpack,
                                                     const float* __restrict__ C0,
                                                     u16* __restrict__ HsBuf,
                                                     float* __restrict__ out,
                                                     unsigned* __restrict__ cnt) {
    extern __shared__ char smem[];
    u16*   Wlds = (u16*)smem;                 // 131072 B, frag-packed
    float* Gbuf = (float*)(smem + 131072);    // 64*68*4 = 17408 B (also warm scratch)
    const int tid  = threadIdx.x;
    const int lane = tid & 63;
    const int w    = tid >> 6;
    const int j    = blockIdx.x;
    const int ln   = lane & 31;
    const int kh   = lane >> 5;
    const int bt   = w >> 1;
    const int ct   = w & 1;

    {   // stage packed W slice (128 KB contiguous, coalesced)
        const uint4* wsrc = (const uint4*)Wpack + (size_t)j * 8192;
        uint4* wdst = (uint4*)Wlds;
        for (int i = tid; i < 8192; i += 256) wdst[i] = wsrc[i];
    }

    // pointwise mapping: thread -> (batch row pb, 4 consecutive h at 16j+hq)
    const int pb = tid >> 2;
    const int hq = (tid & 3) * 4;
    f32x4 c_reg = *(const f32x4*)(C0 + (size_t)pb * 1024 + 16 * j + hq);

    __syncthreads();

    unsigned* leaf = cnt + (j & 7) * 32;   // 8 leaves, 128 B apart
    unsigned* root = cnt + 512;            // separate line
    const u16* wbase = Wlds + ct * 32768 + lane * 8;
    const int slice = j >> 3;              // co-XCD WGs (j%8 alike) cover 8 distinct slices

    // X prefetch for t=0 (layout: [t][j][b][(h&15)][g], g fastest)
    s16x8 xlo, xhi;
    {
        const u16* xb0 = Xp + (size_t)j * 4096 + (size_t)pb * 64 + (size_t)hq * 4;
        xlo = *(const s16x8*)(xb0);
        xhi = *(const s16x8*)(xb0 + 8);
    }

    for (int t = 0; t < T_LEN; ++t) {
        const u16* Hbase = HsBuf + (size_t)t * 65536;

        // --- warm XCD-L2 with our 16 KB slice of H_t (fire-and-forget into scratch) ---
        #pragma unroll
        for (int i = 0; i < 4; ++i) {
            const u16* gp = Hbase + (size_t)slice * 8192 + (size_t)w * 2048 + i * 512 + lane * 8;
            __builtin_amdgcn_global_load_lds(
                (const __attribute__((address_space(1))) unsigned int*)gp,
                (__attribute__((address_space(3))) unsigned int*)
                    ((char*)Gbuf + w * 4096 + i * 1024),
                16, 0, 0);
        }

        // --- MFMA: G = H_t @ W slice; A-loads wave-contiguous 1 KB (Hp layout) ---
        const u16* hrow = Hbase + (size_t)(bt * 32 + ln) * 16 + kh * 8;
        f32x16 acc0 = {};
        f32x16 acc1 = {};
        #pragma unroll 8
        for (int kc = 0; kc < 64; kc += 2) {
            s16x8 a0 = *(const s16x8*)(hrow + (size_t)kc * 1024);
            s16x8 a1 = *(const s16x8*)(hrow + (size_t)kc * 1024 + 1024);
            s16x8 b0 = *(const s16x8*)(wbase + kc * 512);
            s16x8 b1 = *(const s16x8*)(wbase + kc * 512 + 512);
            acc0 = __builtin_amdgcn_mfma_f32_32x32x16_bf16(a0, b0, acc0, 0, 0, 0);
            acc1 = __builtin_amdgcn_mfma_f32_32x32x16_bf16(a1, b1, acc1, 0, 0, 0);
        }
        // all warm-DMA into Gbuf scratch must land before real G writes (all waves)
        asm volatile("s_waitcnt vmcnt(0)" ::: "memory");
        __syncthreads();
        // C/D layout 32x32: col = lane&31, row = (reg&3) + 8*(reg>>2) + 4*(lane>>5)
        #pragma unroll
        for (int r = 0; r < 16; ++r) {
            int row = bt * 32 + (r & 3) + 8 * (r >> 2) + 4 * kh;
            Gbuf[row * GLD + ct * 32 + ln] = acc0[r] + acc1[r];
        }
        __syncthreads();

        // --- pointwise: vector Gbuf reads, 1 dwordx2 write-through H store ---
        const float* gp = Gbuf + pb * GLD + hq;
        f32x4 gI = *(const f32x4*)(gp);
        f32x4 gF = *(const f32x4*)(gp + 16);
        f32x4 gO = *(const f32x4*)(gp + 32);
        f32x4 gC = *(const f32x4*)(gp + 48);
        unsigned long long hv = 0ull;
        f32x4 hnv;
        #pragma unroll
        for (int i = 0; i < 4; ++i) {
            s16x8 xv = (i < 2) ? xlo : xhi;
            int base = (i & 1) * 4;
            float I  = sigmoidf_(gI[i] + b2f((u16)xv[base + 0]));
            float F  = sigmoidf_(gF[i] + b2f((u16)xv[base + 1]));
            float O  = sigmoidf_(gO[i] + b2f((u16)xv[base + 2]));
            float Ct = tanhf_   (gC[i] + b2f((u16)xv[base + 3]));
            float cn = F * c_reg[i] + I * Ct;
            c_reg[i] = cn;
            float hn = O * tanhf_(cn);
            hnv[i] = hn;
            hv |= (unsigned long long)f2b(hn) << (16 * i);
        }

        // --- prefetch next-step X (HBM latency hides under drain + barrier) ---
        if (t + 1 < T_LEN) {
            const u16* xbn = Xp + (size_t)(t + 1) * 262144 + (size_t)j * 4096 +
                             (size_t)pb * 64 + (size_t)hq * 4;
            xlo = *(const s16x8*)(xbn);
            xhi = *(const s16x8*)(xbn + 8);
        }

        // --- write-through H store: 8 B/thread, 512 B contiguous per wave ---
        u16* dst = HsBuf + (size_t)(t + 1) * 65536 + (size_t)j * 1024 + pb * 16 + hq;
        asm volatile("global_store_dwordx2 %0, %1, off sc0 sc1"
                     :: "v"(dst), "v"(hv) : "memory");

        if (t == T_LEN - 1) {
            *(float4*)(out + 16777216 + (size_t)pb * 1024 + 16 * j + hq) = *(float4*)&hnv;          // Hf
            *(float4*)(out + 16777216 + 65536 + (size_t)pb * 1024 + 16 * j + hq) = *(float4*)&c_reg; // Cf
            break;
        }

        // release: drain asm stores, sync waves, then two-level device barrier
        asm volatile("s_waitcnt vmcnt(0)" ::: "memory");
        __syncthreads();
        if (tid == 0) {
            unsigned old = __hip_atomic_fetch_add(leaf, 1u, __ATOMIC_RELAXED,
                                                  __HIP_MEMORY_SCOPE_AGENT);
            if (old == 8u * (unsigned)t + 7u)
                __hip_atomic_fetch_add(root, 1u, __ATOMIC_RELAXED, __HIP_MEMORY_SCOPE_AGENT);
            unsigned tgt = 8u * (unsigned)(t + 1);
            while (__hip_atomic_load(root, __ATOMIC_RELAXED, __HIP_MEMORY_SCOPE_AGENT) < tgt)
                __builtin_amdgcn_s_sleep(2);
        }
        __syncthreads();
    }
}

// ---------- workspace layout (bytes) ----------
//   0         : cnt[1024] (leaves at dword (j&7)*32, root at dword 512)   4096 B
//   4096      : fused bias f32[4096]                                     16384 B
//   20480     : 9 transposed bf16 weights, 2 MB each (Wxi..Wxc, Whi..Whc, Whq)
//   18894848  : Wpack bf16, MFMA-frag order                            8388608 B
//   27283456  : Xbf  bf16 [16384][1024]                               33554432 B
//   60837888  : Xp   bf16 permuted [t][h>>4][b][h&15][g]             134217728 B
//   195055616 : HsBuf bf16 [257] chunks, Hp layout [k>>4][b][k&15]    33685504 B
extern "C" void kernel_launch(void* const* d_in, const int* in_sizes, int n_in,
                              void* d_out, int out_size, void* d_ws, size_t ws_size,
                              hipStream_t stream) {
    const float* inputs = (const float*)d_in[0];
    const float* H0   = (const float*)d_in[1];
    const float* C0   = (const float*)d_in[2];
    const float* W_xi = (const float*)d_in[3];
    const float* W_hi = (const float*)d_in[4];
    const float* b_i  = (const float*)d_in[5];
    const float* W_xf = (const float*)d_in[6];
    const float* W_hf = (const float*)d_in[7];
    const float* b_f  = (const float*)d_in[8];
    const float* W_xo = (const float*)d_in[9];
    const float* W_ho = (const float*)d_in[10];
    const float* b_o  = (const float*)d_in[11];
    const float* W_xc = (const float*)d_in[12];
    const float* W_hc = (const float*)d_in[13];
    const float* b_c  = (const float*)d_in[14];
    const float* W_hq = (const float*)d_in[15];
    const float* b_q  = (const float*)d_in[16];

    float* out = (float*)d_out;
    char* ws = (char*)d_ws;
    unsigned* cnt  = (unsigned*)ws;
    float* fbias   = (float*)(ws + 4096);
    u16* WT        = (u16*)(ws + 20480);
    u16* Wpack     = (u16*)(ws + 18894848);
    u16* Xbf       = (u16*)(ws + 27283456);
    u16* Xp        = (u16*)(ws + 60837888);
    u16* HsBuf     = (u16*)(ws + 195055616);

    f32_to_bf16<<<16384, 256, 0, stream>>>((const float4*)inputs, (ushort4*)Xbf, 4194304);

    const float* wsrcs[9] = {W_xi, W_xf, W_xo, W_xc, W_hi, W_hf, W_ho, W_hc, W_hq};
    for (int i = 0; i < 9; ++i)
        transpose_f32_bf16<<<dim3(16, 16), 256, 0, stream>>>(wsrcs[i], WT + (size_t)i * 1048576);

    init_misc<<<256, 256, 0, stream>>>(H0, HsBuf, cnt, b_i, b_f, b_o, b_c, fbias);
    pack_wh<<<2048, 256, 0, stream>>>(WT + (size_t)4 * 1048576, Wpack);

    // fused input projection -> permuted X layout
    gemm_bt<<<dim3(128, 32), 256, 0, stream>>>(Xbf, WT, fbias, Xp, (float*)nullptr,
                                               16384, 1024, 4096, 1, 0);

    (void)hipFuncSetAttribute((const void*)lstm_steps,
                              hipFuncAttributeMaxDynamicSharedMemorySize, 148480);
    lstm_steps<<<NWG, 256, 148480, stream>>>(Xp, Wpack, C0, HsBuf, out, cnt);

    // outputs = Hs @ W_hq + b_q (fp32 out), A in Hp layout
    gemm_bt<<<dim3(128, 8), 256, 0, stream>>>(HsBuf + 65536, WT + (size_t)8 * 1048576, b_q,
                                              (u16*)nullptr, out, 16384, 1024, 1024, 0, 1);
}

// Round 5
// 2331.031 us; speedup vs baseline: 1.3965x; 1.1694x over previous
//
#include <hip/hip_runtime.h>
#include <cstdint>

typedef unsigned short u16;
typedef __attribute__((ext_vector_type(8))) short s16x8;    // 8 bf16 (4 VGPRs)
typedef __attribute__((ext_vector_type(4))) float f32x4;    // 16x16 MFMA C/D frag
typedef __attribute__((ext_vector_type(16))) float f32x16;  // 32x32 MFMA C/D frag

#define T_LEN 256
#define BATCH 64
#define HID   1024
#define NWG   64

// ---------- bf16 helpers ----------
__device__ __forceinline__ float b2f(u16 u) {
    union { unsigned u; float f; } v; v.u = ((unsigned)u) << 16; return v.f;
}
__device__ __forceinline__ u16 f2b(float f) {
    union { float f; unsigned u; } v; v.f = f;
    unsigned u = v.u;
    return (u16)((u + 0x7fffu + ((u >> 16) & 1u)) >> 16);
}
__device__ __forceinline__ float sigmoidf_(float x) { return 1.0f / (1.0f + __expf(-x)); }
__device__ __forceinline__ float tanhf_(float x) {
    float e = __expf(2.0f * x);
    return 1.0f - 2.0f / (e + 1.0f);
}

// ---------- fp32 -> bf16 bulk convert ----------
__global__ __launch_bounds__(256) void f32_to_bf16(const float4* __restrict__ in,
                                                   ushort4* __restrict__ out, int n4) {
    int i = blockIdx.x * 256 + threadIdx.x;
    if (i < n4) {
        float4 v = in[i];
        ushort4 o;
        o.x = f2b(v.x); o.y = f2b(v.y); o.z = f2b(v.z); o.w = f2b(v.w);
        out[i] = o;
    }
}

// ---------- transpose 1024x1024: out_bf16[c][r] = (bf16)in_f32[r][c] ----------
__global__ __launch_bounds__(256) void transpose_f32_bf16(const float* __restrict__ in,
                                                          u16* __restrict__ out) {
    __shared__ u16 tile[64][65];
    int tx = threadIdx.x & 63, ty = threadIdx.x >> 6;
    int r0 = blockIdx.y * 64, c0 = blockIdx.x * 64;
    for (int r = ty; r < 64; r += 4)
        tile[r][tx] = f2b(in[(size_t)(r0 + r) * 1024 + c0 + tx]);
    __syncthreads();
    for (int c = ty; c < 64; c += 4)
        out[(size_t)(c0 + c) * 1024 + r0 + tx] = tile[tx][c];
}

// ---------- init: counters, fused bias, HsBuf[0] = (bf16)H0 in Hp layout ----------
// Hp layout per step-chunk (65536 u16): off(b,k) = (k>>4)*1024 + b*16 + (k&15)
__global__ __launch_bounds__(256) void init_misc(const float* __restrict__ H0,
                                                 u16* __restrict__ HsBuf,
                                                 unsigned* __restrict__ cnt,
                                                 const float* __restrict__ b_i,
                                                 const float* __restrict__ b_f,
                                                 const float* __restrict__ b_o,
                                                 const float* __restrict__ b_c,
                                                 float* __restrict__ fbias) {
    int i = blockIdx.x * 256 + threadIdx.x;   // grid 256x256 = 65536
    if (i < 1024) cnt[i] = 0u;
    if (i < 4096) {
        int g = i >> 10, k = i & 1023;
        const float* bp = (g == 0) ? b_i : (g == 1) ? b_f : (g == 2) ? b_o : b_c;
        fbias[i] = bp[k];
    }
    if (i < BATCH * HID) {
        int b = i >> 10, k = i & 1023;
        HsBuf[(size_t)(k >> 4) * 1024 + b * 16 + (k & 15)] = f2b(H0[i]);
    }
}

// ---------- pack W_h (4 mats, [h][k] transposed layout) into MFMA-frag order ----
__global__ __launch_bounds__(256) void pack_wh(const u16* __restrict__ WThT,
                                               u16* __restrict__ Wpack) {
    size_t idx = (size_t)blockIdx.x * 256 + threadIdx.x;  // 0..524287
    int lane = idx & 63;
    int kc   = (idx >> 6) & 63;
    int ct   = (idx >> 12) & 1;
    int j    = (int)(idx >> 13);
    int ln = lane & 31, kh = lane >> 5;
    int col = ct * 32 + ln;
    int g = col >> 4, hi = col & 15;
    const uint4* src = (const uint4*)(WThT + (size_t)g * 1048576 +
                                      (size_t)(16 * j + hi) * 1024 + kc * 16 + kh * 8);
    ((uint4*)Wpack)[idx] = *src;
}

// ---------- GEMM: C[m][col] = A[m][:] . BT[col][:] + bias[col] ----------
// mode 0: Cf fp32 row-major [M][ldc].  mode 1: Cb bf16 permuted X layout (g fastest)
//   off(t,b,g,h) = t*262144 + (h>>4)*4096 + b*64 + (h&15)*4 + g, row=t*64+b, col=g*1024+h
// aperm: A is in Hp layout (per-64-row chunk of 65536 u16, off = (k>>4)*1024 + b*16 + (k&15))
__global__ __launch_bounds__(256) void gemm_bt(const u16* __restrict__ A,
                                               const u16* __restrict__ BT,
                                               const float* __restrict__ bias,
                                               u16* __restrict__ Cb,
                                               float* __restrict__ Cf,
                                               int M, int K, int ldc, int xperm, int aperm) {
    __shared__ __align__(16) u16 As[128 * 32];
    __shared__ __align__(16) u16 Bs[128 * 32];
    const int tid  = threadIdx.x;
    const int lane = tid & 63;
    const int w    = tid >> 6;
    const int wm   = (w >> 1) * 64;
    const int wn   = (w & 1) * 64;
    const long m0 = (long)blockIdx.x * 128;
    const long n0 = (long)blockIdx.y * 128;
    const int lrow = lane & 15;
    const int lq   = lane >> 4;

    f32x4 acc[4][4];
    const f32x4 vzero = {0.f, 0.f, 0.f, 0.f};
    #pragma unroll
    for (int i = 0; i < 4; ++i)
        #pragma unroll
        for (int j = 0; j < 4; ++j) acc[i][j] = vzero;

    for (int k0 = 0; k0 < K; k0 += 32) {
        __syncthreads();
        #pragma unroll
        for (int i = 0; i < 2; ++i) {
            int chunk = i * 256 + w * 64 + lane;
            const u16* ga;
            if (aperm) {
                long row = m0 + (chunk >> 2);
                int  c   = chunk & 3;
                ga = A + (row >> 6) * 65536L + (long)((k0 >> 4) + (c >> 1)) * 1024 +
                     (row & 63) * 16 + (c & 1) * 8;
            } else {
                ga = A + (m0 + (chunk >> 2)) * (long)K + k0 + (chunk & 3) * 8;
            }
            __builtin_amdgcn_global_load_lds(
                (const __attribute__((address_space(1))) unsigned int*)ga,
                (__attribute__((address_space(3))) unsigned int*)(As + (i * 256 + w * 64) * 8),
                16, 0, 0);
            const u16* gb = BT + (n0 + (chunk >> 2)) * (long)K + k0 + (chunk & 3) * 8;
            __builtin_amdgcn_global_load_lds(
                (const __attribute__((address_space(1))) unsigned int*)gb,
                (__attribute__((address_space(3))) unsigned int*)(Bs + (i * 256 + w * 64) * 8),
                16, 0, 0);
        }
        __syncthreads();
        s16x8 af[4], bf[4];
        #pragma unroll
        for (int i = 0; i < 4; ++i)
            af[i] = *(const s16x8*)(As + (wm + i * 16 + lrow) * 32 + lq * 8);
        #pragma unroll
        for (int j = 0; j < 4; ++j)
            bf[j] = *(const s16x8*)(Bs + (wn + j * 16 + lrow) * 32 + lq * 8);
        #pragma unroll
        for (int i = 0; i < 4; ++i)
            #pragma unroll
            for (int j = 0; j < 4; ++j)
                acc[i][j] = __builtin_amdgcn_mfma_f32_16x16x32_bf16(af[i], bf[j], acc[i][j], 0, 0, 0);
    }
    #pragma unroll
    for (int j = 0; j < 4; ++j) {
        long col = n0 + wn + j * 16 + lrow;
        float bv = bias[col];
        #pragma unroll
        for (int i = 0; i < 4; ++i) {
            long rowb = m0 + wm + i * 16 + lq * 4;
            #pragma unroll
            for (int r = 0; r < 4; ++r) {
                float v = acc[i][j][r] + bv;
                long row = rowb + r;
                if (xperm) {
                    long t = row >> 6, b = row & 63;
                    long g = col >> 10, h = col & 1023;
                    Cb[t * 262144 + (h >> 4) * 4096 + b * 64 + (h & 15) * 4 + g] = f2b(v);
                } else {
                    Cf[row * (long)ldc + col] = v;
                }
            }
        }
    }
}

// ---------- persistent LSTM recurrence: 64 WGs, 1 barrier/step ----------
// WG j owns cols c = g*16+hi (4 gates x 16 h), h = 16j+hi.
// K-SPLIT: wave (bt,ct) computes a PARTIAL 32x64 G tile over k in
// [ct*512,(ct+1)*512) -- both col-tiles, zero A duplication (128 KB/CU/step
// instead of 256 KB; L1-fill at ~56 B/cy was ~1.9 us/step). W stays in LDS
// (round-1's W-in-regs blowup avoided); same Wpack layout, indexed by
// chunk range [ct*32, ct*32+32) of both col-tile planes.
// Gbuf[2][64][64] partial halves, 4-dword-group XOR swizzle (group ^= row&15):
// writes cover all 32 banks per 32-lane group; pointwise sums the halves.
// H in Hp layout [t][k>>4][b][k&15]: A-loads wave-contiguous 1 KB, H stores
// one dwordx2/thread (512 B contiguous/wave).
// L2 warming (PROVEN x2, rounds 3/4): co-XCD WGs stream H_t slices into
// Gbuf-scratch so MFMA A-loads hit warm XCD-L2 instead of MALL round-trips.
// X prefetch issued at TOP of step (round 4 issued it inside the release
// drain -- full HBM RT on the serial chain); absorbed by post-MFMA vmcnt(0).
// Barrier: leaf+root two-level. Write-through H stores (sc0 sc1).
__global__ __launch_bounds__(256, 1) void lstm_steps(const u16* __restrict__ Xp,
                                                     const u16* __restrict__ Wpack,
                                                     const float* __restrict__ C0,
                                                     u16* __restrict__ HsBuf,
                                                     float* __restrict__ out,
                                                     unsigned* __restrict__ cnt) {
    extern __shared__ char smem[];
    u16*   Wlds = (u16*)smem;                 // 131072 B, frag-packed
    float* Gbuf = (float*)(smem + 131072);    // 2*64*64*4 = 32768 B (also warm scratch)
    const int tid  = threadIdx.x;
    const int lane = tid & 63;
    const int w    = tid >> 6;
    const int j    = blockIdx.x;
    const int ln   = lane & 31;
    const int kh   = lane >> 5;
    const int bt   = w >> 1;     // row half (32 b-rows)
    const int ct   = w & 1;      // K half (512 k)

    {   // stage packed W slice (128 KB contiguous, coalesced)
        const uint4* wsrc = (const uint4*)Wpack + (size_t)j * 8192;
        uint4* wdst = (uint4*)Wlds;
        for (int i = tid; i < 8192; i += 256) wdst[i] = wsrc[i];
    }

    // pointwise mapping: thread -> (batch row pb, 4 consecutive h at 16j+hq)
    const int pb = tid >> 2;
    const int hq = (tid & 3) * 4;
    const int cg = tid & 3;        // Gbuf col group (hq>>2)
    const int pm = pb & 15;        // row swizzle key
    f32x4 c_reg = *(const f32x4*)(C0 + (size_t)pb * 1024 + 16 * j + hq);

    __syncthreads();

    unsigned* leaf = cnt + (j & 7) * 32;   // 8 leaves, 128 B apart
    unsigned* root = cnt + 512;            // separate line
    // this wave's W frag bases: chunk range [ct*32, ct*32+32) of both col-tiles
    const u16* wb0 = Wlds + (size_t)(ct * 32) * 512 + lane * 8;           // cols 0..31
    const u16* wb1 = Wlds + 32768 + (size_t)(ct * 32) * 512 + lane * 8;   // cols 32..63
    const int slice = j >> 3;              // co-XCD WGs (j%8 alike) cover 8 distinct slices

    // X for t=0 (layout: [t][j][b][(h&15)][g], g fastest) + prefetch regs
    s16x8 xlo, xhi, xnlo, xnhi;
    {
        const u16* xb0 = Xp + (size_t)j * 4096 + (size_t)pb * 64 + (size_t)hq * 4;
        xlo = *(const s16x8*)(xb0);
        xhi = *(const s16x8*)(xb0 + 8);
    }

    for (int t = 0; t < T_LEN; ++t) {
        const u16* Hbase = HsBuf + (size_t)t * 65536;

        // --- warm XCD-L2 with our 16 KB slice of H_t (fire-and-forget into scratch) ---
        #pragma unroll
        for (int i = 0; i < 4; ++i) {
            const u16* gp = Hbase + (size_t)slice * 8192 + (size_t)w * 2048 + i * 512 + lane * 8;
            __builtin_amdgcn_global_load_lds(
                (const __attribute__((address_space(1))) unsigned int*)gp,
                (__attribute__((address_space(3))) unsigned int*)
                    ((char*)Gbuf + w * 4096 + i * 1024),
                16, 0, 0);
        }

        // --- X prefetch for t+1 at step TOP: HBM latency hides under MFMA ---
        if (t + 1 < T_LEN) {
            const u16* xbn = Xp + (size_t)(t + 1) * 262144 + (size_t)j * 4096 +
                             (size_t)pb * 64 + (size_t)hq * 4;
            xnlo = *(const s16x8*)(xbn);
            xnhi = *(const s16x8*)(xbn + 8);
        }

        // --- MFMA (K-split): partial G over this wave's K half, both col-tiles ---
        const u16* hb2 = Hbase + (size_t)ct * 32768 + (size_t)(bt * 32 + ln) * 16 + kh * 8;
        f32x16 acc0 = {};
        f32x16 acc1 = {};
        #pragma unroll 8
        for (int kc = 0; kc < 32; ++kc) {
            s16x8 a  = *(const s16x8*)(hb2 + (size_t)kc * 1024);
            s16x8 b0 = *(const s16x8*)(wb0 + kc * 512);
            s16x8 b1 = *(const s16x8*)(wb1 + kc * 512);
            acc0 = __builtin_amdgcn_mfma_f32_32x32x16_bf16(a, b0, acc0, 0, 0, 0);
            acc1 = __builtin_amdgcn_mfma_f32_32x32x16_bf16(a, b1, acc1, 0, 0, 0);
        }
        // warm-DMA + X-prefetch must land before Gbuf is overwritten (all waves)
        asm volatile("s_waitcnt vmcnt(0)" ::: "memory");
        __syncthreads();
        // partial-G writes, XOR-swizzled: dword (row*64 + ((colgrp^row&15)<<2) + col&3)
        // C/D layout 32x32: col = lane&31, row = (reg&3) + 8*(reg>>2) + 4*(lane>>5)
        #pragma unroll
        for (int r = 0; r < 16; ++r) {
            int row = bt * 32 + (r & 3) + 8 * (r >> 2) + 4 * kh;
            int rm  = row & 15;
            float* gr = Gbuf + ct * 4096 + row * 64;
            gr[(((ln >> 2) ^ rm) << 2) + (ln & 3)]       = acc0[r];   // col = ln
            gr[((((ln >> 2) + 8) ^ rm) << 2) + (ln & 3)] = acc1[r];   // col = 32+ln
        }
        __syncthreads();

        // --- pointwise: sum K halves (swizzled b128 reads), dwordx2 H store ---
        const float* g0 = Gbuf + pb * 64;
        const float* g1 = Gbuf + 4096 + pb * 64;
        f32x4 gI = *(const f32x4*)(g0 + ((cg ^ pm) << 2))        + *(const f32x4*)(g1 + ((cg ^ pm) << 2));
        f32x4 gF = *(const f32x4*)(g0 + (((cg + 4) ^ pm) << 2))  + *(const f32x4*)(g1 + (((cg + 4) ^ pm) << 2));
        f32x4 gO = *(const f32x4*)(g0 + (((cg + 8) ^ pm) << 2))  + *(const f32x4*)(g1 + (((cg + 8) ^ pm) << 2));
        f32x4 gC = *(const f32x4*)(g0 + (((cg + 12) ^ pm) << 2)) + *(const f32x4*)(g1 + (((cg + 12) ^ pm) << 2));
        unsigned long long hv = 0ull;
        f32x4 hnv;
        #pragma unroll
        for (int i = 0; i < 4; ++i) {
            s16x8 xv = (i < 2) ? xlo : xhi;
            int base = (i & 1) * 4;
            float I  = sigmoidf_(gI[i] + b2f((u16)xv[base + 0]));
            float F  = sigmoidf_(gF[i] + b2f((u16)xv[base + 1]));
            float O  = sigmoidf_(gO[i] + b2f((u16)xv[base + 2]));
            float Ct = tanhf_   (gC[i] + b2f((u16)xv[base + 3]));
            float cn = F * c_reg[i] + I * Ct;
            c_reg[i] = cn;
            float hn = O * tanhf_(cn);
            hnv[i] = hn;
            hv |= (unsigned long long)f2b(hn) << (16 * i);
        }

        // --- write-through H store: 8 B/thread, 512 B contiguous per wave ---
        u16* dst = HsBuf + (size_t)(t + 1) * 65536 + (size_t)j * 1024 + pb * 16 + hq;
        asm volatile("global_store_dwordx2 %0, %1, off sc0 sc1"
                     :: "v"(dst), "v"(hv) : "memory");

        if (t == T_LEN - 1) {
            *(float4*)(out + 16777216 + (size_t)pb * 1024 + 16 * j + hq) = *(float4*)&hnv;           // Hf
            *(float4*)(out + 16777216 + 65536 + (size_t)pb * 1024 + 16 * j + hq) = *(float4*)&c_reg; // Cf
            break;
        }

        // rotate X prefetch regs (reg-only, overlaps drain)
        xlo = xnlo; xhi = xnhi;

        // release: drain H store, sync waves, then two-level device barrier
        asm volatile("s_waitcnt vmcnt(0)" ::: "memory");
        __syncthreads();
        if (tid == 0) {
            unsigned old = __hip_atomic_fetch_add(leaf, 1u, __ATOMIC_RELAXED,
                                                  __HIP_MEMORY_SCOPE_AGENT);
            if (old == 8u * (unsigned)t + 7u)
                __hip_atomic_fetch_add(root, 1u, __ATOMIC_RELAXED, __HIP_MEMORY_SCOPE_AGENT);
            unsigned tgt = 8u * (unsigned)(t + 1);
            while (__hip_atomic_load(root, __ATOMIC_RELAXED, __HIP_MEMORY_SCOPE_AGENT) < tgt)
                __builtin_amdgcn_s_sleep(2);
        }
        __syncthreads();
    }
}

// ---------- workspace layout (bytes) ----------
//   0         : cnt[1024] (leaves at dword (j&7)*32, root at dword 512)   4096 B
//   4096      : fused bias f32[4096]                                     16384 B
//   20480     : 9 transposed bf16 weights, 2 MB each (Wxi..Wxc, Whi..Whc, Whq)
//   18894848  : Wpack bf16, MFMA-frag order                            8388608 B
//   27283456  : Xbf  bf16 [16384][1024]                               33554432 B
//   60837888  : Xp   bf16 permuted [t][h>>4][b][h&15][g]             134217728 B
//   195055616 : HsBuf bf16 [257] chunks, Hp layout [k>>4][b][k&15]    33685504 B
extern "C" void kernel_launch(void* const* d_in, const int* in_sizes, int n_in,
                              void* d_out, int out_size, void* d_ws, size_t ws_size,
                              hipStream_t stream) {
    const float* inputs = (const float*)d_in[0];
    const float* H0   = (const float*)d_in[1];
    const float* C0   = (const float*)d_in[2];
    const float* W_xi = (const float*)d_in[3];
    const float* W_hi = (const float*)d_in[4];
    const float* b_i  = (const float*)d_in[5];
    const float* W_xf = (const float*)d_in[6];
    const float* W_hf = (const float*)d_in[7];
    const float* b_f  = (const float*)d_in[8];
    const float* W_xo = (const float*)d_in[9];
    const float* W_ho = (const float*)d_in[10];
    const float* b_o  = (const float*)d_in[11];
    const float* W_xc = (const float*)d_in[12];
    const float* W_hc = (const float*)d_in[13];
    const float* b_c  = (const float*)d_in[14];
    const float* W_hq = (const float*)d_in[15];
    const float* b_q  = (const float*)d_in[16];

    float* out = (float*)d_out;
    char* ws = (char*)d_ws;
    unsigned* cnt  = (unsigned*)ws;
    float* fbias   = (float*)(ws + 4096);
    u16* WT        = (u16*)(ws + 20480);
    u16* Wpack     = (u16*)(ws + 18894848);
    u16* Xbf       = (u16*)(ws + 27283456);
    u16* Xp        = (u16*)(ws + 60837888);
    u16* HsBuf     = (u16*)(ws + 195055616);

    f32_to_bf16<<<16384, 256, 0, stream>>>((const float4*)inputs, (ushort4*)Xbf, 4194304);

    const float* wsrcs[9] = {W_xi, W_xf, W_xo, W_xc, W_hi, W_hf, W_ho, W_hc, W_hq};
    for (int i = 0; i < 9; ++i)
        transpose_f32_bf16<<<dim3(16, 16), 256, 0, stream>>>(wsrcs[i], WT + (size_t)i * 1048576);

    init_misc<<<256, 256, 0, stream>>>(H0, HsBuf, cnt, b_i, b_f, b_o, b_c, fbias);
    pack_wh<<<2048, 256, 0, stream>>>(WT + (size_t)4 * 1048576, Wpack);

    // fused input projection -> permuted X layout
    gemm_bt<<<dim3(128, 32), 256, 0, stream>>>(Xbf, WT, fbias, Xp, (float*)nullptr,
                                               16384, 1024, 4096, 1, 0);

    (void)hipFuncSetAttribute((const void*)lstm_steps,
                              hipFuncAttributeMaxDynamicSharedMemorySize, 163840);
    lstm_steps<<<NWG, 256, 163840, stream>>>(Xp, Wpack, C0, HsBuf, out, cnt);

    // outputs = Hs @ W_hq + b_q (fp32 out), A in Hp layout
    gemm_bt<<<dim3(128, 8), 256, 0, stream>>>(HsBuf + 65536, WT + (size_t)8 * 1048576, b_q,
                                              (u16*)nullptr, out, 16384, 1024, 1024, 0, 1);
}

// Round 6
// 2202.798 us; speedup vs baseline: 1.4778x; 1.0582x over previous
//
#include <hip/hip_runtime.h>
#include <cstdint>

typedef unsigned short u16;
typedef __attribute__((ext_vector_type(8))) short s16x8;    // 8 bf16 (4 VGPRs)
typedef __attribute__((ext_vector_type(4))) float f32x4;    // 16x16 MFMA C/D frag
typedef __attribute__((ext_vector_type(16))) float f32x16;  // 32x32 MFMA C/D frag

#define T_LEN 256
#define BATCH 64
#define HID   1024
#define NWG   64

// ---------- bf16 helpers ----------
__device__ __forceinline__ float b2f(u16 u) {
    union { unsigned u; float f; } v; v.u = ((unsigned)u) << 16; return v.f;
}
__device__ __forceinline__ u16 f2b(float f) {
    union { float f; unsigned u; } v; v.f = f;
    unsigned u = v.u;
    return (u16)((u + 0x7fffu + ((u >> 16) & 1u)) >> 16);
}
__device__ __forceinline__ float sigmoidf_(float x) { return 1.0f / (1.0f + __expf(-x)); }
__device__ __forceinline__ float tanhf_(float x) {
    float e = __expf(2.0f * x);
    return 1.0f - 2.0f / (e + 1.0f);
}

// ---------- fp32 -> bf16 bulk convert ----------
__global__ __launch_bounds__(256) void f32_to_bf16(const float4* __restrict__ in,
                                                   ushort4* __restrict__ out, int n4) {
    int i = blockIdx.x * 256 + threadIdx.x;
    if (i < n4) {
        float4 v = in[i];
        ushort4 o;
        o.x = f2b(v.x); o.y = f2b(v.y); o.z = f2b(v.z); o.w = f2b(v.w);
        out[i] = o;
    }
}

// ---------- transpose 1024x1024: out_bf16[c][r] = (bf16)in_f32[r][c] ----------
__global__ __launch_bounds__(256) void transpose_f32_bf16(const float* __restrict__ in,
                                                          u16* __restrict__ out) {
    __shared__ u16 tile[64][65];
    int tx = threadIdx.x & 63, ty = threadIdx.x >> 6;
    int r0 = blockIdx.y * 64, c0 = blockIdx.x * 64;
    for (int r = ty; r < 64; r += 4)
        tile[r][tx] = f2b(in[(size_t)(r0 + r) * 1024 + c0 + tx]);
    __syncthreads();
    for (int c = ty; c < 64; c += 4)
        out[(size_t)(c0 + c) * 1024 + r0 + tx] = tile[tx][c];
}

// ---------- init: counters, fused bias, HsBuf[0] = (bf16)H0 in Hp layout ----------
// Hp layout per step-chunk (65536 u16): off(b,k) = (k>>4)*1024 + b*16 + (k&15)
__global__ __launch_bounds__(256) void init_misc(const float* __restrict__ H0,
                                                 u16* __restrict__ HsBuf,
                                                 unsigned* __restrict__ cnt,
                                                 const float* __restrict__ b_i,
                                                 const float* __restrict__ b_f,
                                                 const float* __restrict__ b_o,
                                                 const float* __restrict__ b_c,
                                                 float* __restrict__ fbias) {
    int i = blockIdx.x * 256 + threadIdx.x;   // grid 256x256 = 65536
    if (i < 1024) cnt[i] = 0u;
    if (i < 4096) {
        int g = i >> 10, k = i & 1023;
        const float* bp = (g == 0) ? b_i : (g == 1) ? b_f : (g == 2) ? b_o : b_c;
        fbias[i] = bp[k];
    }
    if (i < BATCH * HID) {
        int b = i >> 10, k = i & 1023;
        HsBuf[(size_t)(k >> 4) * 1024 + b * 16 + (k & 15)] = f2b(H0[i]);
    }
}

// ---------- pack W_h (4 mats, [h][k] transposed layout) into MFMA-frag order ----
__global__ __launch_bounds__(256) void pack_wh(const u16* __restrict__ WThT,
                                               u16* __restrict__ Wpack) {
    size_t idx = (size_t)blockIdx.x * 256 + threadIdx.x;  // 0..524287
    int lane = idx & 63;
    int kc   = (idx >> 6) & 63;
    int ct   = (idx >> 12) & 1;
    int j    = (int)(idx >> 13);
    int ln = lane & 31, kh = lane >> 5;
    int col = ct * 32 + ln;
    int g = col >> 4, hi = col & 15;
    const uint4* src = (const uint4*)(WThT + (size_t)g * 1048576 +
                                      (size_t)(16 * j + hi) * 1024 + kc * 16 + kh * 8);
    ((uint4*)Wpack)[idx] = *src;
}

// ---------- GEMM: C[m][col] = A[m][:] . BT[col][:] + bias[col] ----------
// mode 0: Cf fp32 row-major [M][ldc].  mode 1: Cb bf16 permuted X layout (g fastest)
//   off(t,b,g,h) = t*262144 + (h>>4)*4096 + b*64 + (h&15)*4 + g, row=t*64+b, col=g*1024+h
// aperm: A is in Hp layout (per-64-row chunk of 65536 u16, off = (k>>4)*1024 + b*16 + (k&15))
__global__ __launch_bounds__(256) void gemm_bt(const u16* __restrict__ A,
                                               const u16* __restrict__ BT,
                                               const float* __restrict__ bias,
                                               u16* __restrict__ Cb,
                                               float* __restrict__ Cf,
                                               int M, int K, int ldc, int xperm, int aperm) {
    __shared__ __align__(16) u16 As[128 * 32];
    __shared__ __align__(16) u16 Bs[128 * 32];
    const int tid  = threadIdx.x;
    const int lane = tid & 63;
    const int w    = tid >> 6;
    const int wm   = (w >> 1) * 64;
    const int wn   = (w & 1) * 64;
    const long m0 = (long)blockIdx.x * 128;
    const long n0 = (long)blockIdx.y * 128;
    const int lrow = lane & 15;
    const int lq   = lane >> 4;

    f32x4 acc[4][4];
    const f32x4 vzero = {0.f, 0.f, 0.f, 0.f};
    #pragma unroll
    for (int i = 0; i < 4; ++i)
        #pragma unroll
        for (int j = 0; j < 4; ++j) acc[i][j] = vzero;

    for (int k0 = 0; k0 < K; k0 += 32) {
        __syncthreads();
        #pragma unroll
        for (int i = 0; i < 2; ++i) {
            int chunk = i * 256 + w * 64 + lane;
            const u16* ga;
            if (aperm) {
                long row = m0 + (chunk >> 2);
                int  c   = chunk & 3;
                ga = A + (row >> 6) * 65536L + (long)((k0 >> 4) + (c >> 1)) * 1024 +
                     (row & 63) * 16 + (c & 1) * 8;
            } else {
                ga = A + (m0 + (chunk >> 2)) * (long)K + k0 + (chunk & 3) * 8;
            }
            __builtin_amdgcn_global_load_lds(
                (const __attribute__((address_space(1))) unsigned int*)ga,
                (__attribute__((address_space(3))) unsigned int*)(As + (i * 256 + w * 64) * 8),
                16, 0, 0);
            const u16* gb = BT + (n0 + (chunk >> 2)) * (long)K + k0 + (chunk & 3) * 8;
            __builtin_amdgcn_global_load_lds(
                (const __attribute__((address_space(1))) unsigned int*)gb,
                (__attribute__((address_space(3))) unsigned int*)(Bs + (i * 256 + w * 64) * 8),
                16, 0, 0);
        }
        __syncthreads();
        s16x8 af[4], bf[4];
        #pragma unroll
        for (int i = 0; i < 4; ++i)
            af[i] = *(const s16x8*)(As + (wm + i * 16 + lrow) * 32 + lq * 8);
        #pragma unroll
        for (int j = 0; j < 4; ++j)
            bf[j] = *(const s16x8*)(Bs + (wn + j * 16 + lrow) * 32 + lq * 8);
        #pragma unroll
        for (int i = 0; i < 4; ++i)
            #pragma unroll
            for (int j = 0; j < 4; ++j)
                acc[i][j] = __builtin_amdgcn_mfma_f32_16x16x32_bf16(af[i], bf[j], acc[i][j], 0, 0, 0);
    }
    #pragma unroll
    for (int j = 0; j < 4; ++j) {
        long col = n0 + wn + j * 16 + lrow;
        float bv = bias[col];
        #pragma unroll
        for (int i = 0; i < 4; ++i) {
            long rowb = m0 + wm + i * 16 + lq * 4;
            #pragma unroll
            for (int r = 0; r < 4; ++r) {
                float v = acc[i][j][r] + bv;
                long row = rowb + r;
                if (xperm) {
                    long t = row >> 6, b = row & 63;
                    long g = col >> 10, h = col & 1023;
                    Cb[t * 262144 + (h >> 4) * 4096 + b * 64 + (h & 15) * 4 + g] = f2b(v);
                } else {
                    Cf[row * (long)ldc + col] = v;
                }
            }
        }
    }
}

// ---------- persistent LSTM recurrence: 64 WGs, 1 barrier/step ----------
// WG j owns cols c = g*16+hi (4 gates x 16 h), h = 16j+hi.
// K-SPLIT (round-5 proven): wave (bt,ct) computes a PARTIAL 32x64 G tile over
// k in [ct*512,(ct+1)*512), both col-tiles, zero A duplication. W in LDS.
// A-MLP (this round): ALL 32 A-fragments preloaded into regs before the MFMA
// loop -- one memory round-trip instead of ~8 serialized (VGPR=72 implied
// MLP~4; round-3's warming ablation measured the A-chain at +2.1us/step).
// launch_bounds(256,1) = 512-VGPR budget at our fixed 1-wave/SIMD occupancy.
// Gbuf[2][64][64] partial halves, XOR-swizzled; pointwise sums the halves.
// H in Hp layout [t][k>>4][b][k&15]: A-loads wave-contiguous 1 KB, H stores
// one dwordx2/thread (512 B contiguous/wave).
// L2 warming (PROVEN x2, rounds 3/4): co-XCD WGs stream H_t slices into
// Gbuf-scratch so early A-loads hit warm XCD-L2.
// X prefetch at step TOP (round-5 proven).
// Barrier: leaf+root two-level; BUSY-poll (no s_sleep) cuts detect latency.
__global__ __launch_bounds__(256, 1) void lstm_steps(const u16* __restrict__ Xp,
                                                     const u16* __restrict__ Wpack,
                                                     const float* __restrict__ C0,
                                                     u16* __restrict__ HsBuf,
                                                     float* __restrict__ out,
                                                     unsigned* __restrict__ cnt) {
    extern __shared__ char smem[];
    u16*   Wlds = (u16*)smem;                 // 131072 B, frag-packed
    float* Gbuf = (float*)(smem + 131072);    // 2*64*64*4 = 32768 B (also warm scratch)
    const int tid  = threadIdx.x;
    const int lane = tid & 63;
    const int w    = tid >> 6;
    const int j    = blockIdx.x;
    const int ln   = lane & 31;
    const int kh   = lane >> 5;
    const int bt   = w >> 1;     // row half (32 b-rows)
    const int ct   = w & 1;      // K half (512 k)

    {   // stage packed W slice (128 KB contiguous, coalesced)
        const uint4* wsrc = (const uint4*)Wpack + (size_t)j * 8192;
        uint4* wdst = (uint4*)Wlds;
        for (int i = tid; i < 8192; i += 256) wdst[i] = wsrc[i];
    }

    // pointwise mapping: thread -> (batch row pb, 4 consecutive h at 16j+hq)
    const int pb = tid >> 2;
    const int hq = (tid & 3) * 4;
    const int cg = tid & 3;        // Gbuf col group (hq>>2)
    const int pm = pb & 15;        // row swizzle key
    f32x4 c_reg = *(const f32x4*)(C0 + (size_t)pb * 1024 + 16 * j + hq);

    __syncthreads();

    unsigned* leaf = cnt + (j & 7) * 32;   // 8 leaves, 128 B apart
    unsigned* root = cnt + 512;            // separate line
    // this wave's W frag bases: chunk range [ct*32, ct*32+32) of both col-tiles
    const u16* wb0 = Wlds + (size_t)(ct * 32) * 512 + lane * 8;           // cols 0..31
    const u16* wb1 = Wlds + 32768 + (size_t)(ct * 32) * 512 + lane * 8;   // cols 32..63
    const int slice = j >> 3;              // co-XCD WGs (j%8 alike) cover 8 distinct slices

    // X for t=0 (layout: [t][j][b][(h&15)][g], g fastest) + prefetch regs
    s16x8 xlo, xhi, xnlo, xnhi;
    {
        const u16* xb0 = Xp + (size_t)j * 4096 + (size_t)pb * 64 + (size_t)hq * 4;
        xlo = *(const s16x8*)(xb0);
        xhi = *(const s16x8*)(xb0 + 8);
    }

    for (int t = 0; t < T_LEN; ++t) {
        const u16* Hbase = HsBuf + (size_t)t * 65536;

        // --- warm XCD-L2 with our 16 KB slice of H_t (fire-and-forget into scratch) ---
        #pragma unroll
        for (int i = 0; i < 4; ++i) {
            const u16* gp = Hbase + (size_t)slice * 8192 + (size_t)w * 2048 + i * 512 + lane * 8;
            __builtin_amdgcn_global_load_lds(
                (const __attribute__((address_space(1))) unsigned int*)gp,
                (__attribute__((address_space(3))) unsigned int*)
                    ((char*)Gbuf + w * 4096 + i * 1024),
                16, 0, 0);
        }

        // --- X prefetch for t+1 at step TOP: HBM latency hides under MFMA ---
        if (t + 1 < T_LEN) {
            const u16* xbn = Xp + (size_t)(t + 1) * 262144 + (size_t)j * 4096 +
                             (size_t)pb * 64 + (size_t)hq * 4;
            xnlo = *(const s16x8*)(xbn);
            xnhi = *(const s16x8*)(xbn + 8);
        }

        // --- A preload: all 32 fragments in flight at once (MLP=32) ---
        const u16* hb2 = Hbase + (size_t)ct * 32768 + (size_t)(bt * 32 + ln) * 16 + kh * 8;
        s16x8 a[32];
        #pragma unroll
        for (int u = 0; u < 32; ++u)
            a[u] = *(const s16x8*)(hb2 + (size_t)u * 1024);

        // --- MFMA (K-split): partial G over this wave's K half, both col-tiles ---
        f32x16 acc0 = {};
        f32x16 acc1 = {};
        #pragma unroll
        for (int kc = 0; kc < 32; ++kc) {
            s16x8 b0 = *(const s16x8*)(wb0 + kc * 512);
            s16x8 b1 = *(const s16x8*)(wb1 + kc * 512);
            acc0 = __builtin_amdgcn_mfma_f32_32x32x16_bf16(a[kc], b0, acc0, 0, 0, 0);
            acc1 = __builtin_amdgcn_mfma_f32_32x32x16_bf16(a[kc], b1, acc1, 0, 0, 0);
        }
        // warm-DMA + X-prefetch must land before Gbuf is overwritten (all waves)
        asm volatile("s_waitcnt vmcnt(0)" ::: "memory");
        __syncthreads();
        // partial-G writes, XOR-swizzled: dword (row*64 + ((colgrp^row&15)<<2) + col&3)
        // C/D layout 32x32: col = lane&31, row = (reg&3) + 8*(reg>>2) + 4*(lane>>5)
        #pragma unroll
        for (int r = 0; r < 16; ++r) {
            int row = bt * 32 + (r & 3) + 8 * (r >> 2) + 4 * kh;
            int rm  = row & 15;
            float* gr = Gbuf + ct * 4096 + row * 64;
            gr[(((ln >> 2) ^ rm) << 2) + (ln & 3)]       = acc0[r];   // col = ln
            gr[((((ln >> 2) + 8) ^ rm) << 2) + (ln & 3)] = acc1[r];   // col = 32+ln
        }
        __syncthreads();

        // --- pointwise: sum K halves (swizzled b128 reads), dwordx2 H store ---
        const float* g0 = Gbuf + pb * 64;
        const float* g1 = Gbuf + 4096 + pb * 64;
        f32x4 gI = *(const f32x4*)(g0 + ((cg ^ pm) << 2))        + *(const f32x4*)(g1 + ((cg ^ pm) << 2));
        f32x4 gF = *(const f32x4*)(g0 + (((cg + 4) ^ pm) << 2))  + *(const f32x4*)(g1 + (((cg + 4) ^ pm) << 2));
        f32x4 gO = *(const f32x4*)(g0 + (((cg + 8) ^ pm) << 2))  + *(const f32x4*)(g1 + (((cg + 8) ^ pm) << 2));
        f32x4 gC = *(const f32x4*)(g0 + (((cg + 12) ^ pm) << 2)) + *(const f32x4*)(g1 + (((cg + 12) ^ pm) << 2));
        unsigned long long hv = 0ull;
        f32x4 hnv;
        #pragma unroll
        for (int i = 0; i < 4; ++i) {
            s16x8 xv = (i < 2) ? xlo : xhi;
            int base = (i & 1) * 4;
            float I  = sigmoidf_(gI[i] + b2f((u16)xv[base + 0]));
            float F  = sigmoidf_(gF[i] + b2f((u16)xv[base + 1]));
            float O  = sigmoidf_(gO[i] + b2f((u16)xv[base + 2]));
            float Ct = tanhf_   (gC[i] + b2f((u16)xv[base + 3]));
            float cn = F * c_reg[i] + I * Ct;
            c_reg[i] = cn;
            float hn = O * tanhf_(cn);
            hnv[i] = hn;
            hv |= (unsigned long long)f2b(hn) << (16 * i);
        }

        // --- write-through H store: 8 B/thread, 512 B contiguous per wave ---
        u16* dst = HsBuf + (size_t)(t + 1) * 65536 + (size_t)j * 1024 + pb * 16 + hq;
        asm volatile("global_store_dwordx2 %0, %1, off sc0 sc1"
                     :: "v"(dst), "v"(hv) : "memory");

        if (t == T_LEN - 1) {
            *(float4*)(out + 16777216 + (size_t)pb * 1024 + 16 * j + hq) = *(float4*)&hnv;           // Hf
            *(float4*)(out + 16777216 + 65536 + (size_t)pb * 1024 + 16 * j + hq) = *(float4*)&c_reg; // Cf
            break;
        }

        // rotate X prefetch regs (reg-only, overlaps drain)
        xlo = xnlo; xhi = xnhi;

        // release: drain H store, sync waves, then two-level device barrier
        asm volatile("s_waitcnt vmcnt(0)" ::: "memory");
        __syncthreads();
        if (tid == 0) {
            unsigned old = __hip_atomic_fetch_add(leaf, 1u, __ATOMIC_RELAXED,
                                                  __HIP_MEMORY_SCOPE_AGENT);
            if (old == 8u * (unsigned)t + 7u)
                __hip_atomic_fetch_add(root, 1u, __ATOMIC_RELAXED, __HIP_MEMORY_SCOPE_AGENT);
            unsigned tgt = 8u * (unsigned)(t + 1);
            while (__hip_atomic_load(root, __ATOMIC_RELAXED, __HIP_MEMORY_SCOPE_AGENT) < tgt) {}
        }
        __syncthreads();
    }
}

// ---------- workspace layout (bytes) ----------
//   0         : cnt[1024] (leaves at dword (j&7)*32, root at dword 512)   4096 B
//   4096      : fused bias f32[4096]                                     16384 B
//   20480     : 9 transposed bf16 weights, 2 MB each (Wxi..Wxc, Whi..Whc, Whq)
//   18894848  : Wpack bf16, MFMA-frag order                            8388608 B
//   27283456  : Xbf  bf16 [16384][1024]                               33554432 B
//   60837888  : Xp   bf16 permuted [t][h>>4][b][h&15][g]             134217728 B
//   195055616 : HsBuf bf16 [257] chunks, Hp layout [k>>4][b][k&15]    33685504 B
extern "C" void kernel_launch(void* const* d_in, const int* in_sizes, int n_in,
                              void* d_out, int out_size, void* d_ws, size_t ws_size,
                              hipStream_t stream) {
    const float* inputs = (const float*)d_in[0];
    const float* H0   = (const float*)d_in[1];
    const float* C0   = (const float*)d_in[2];
    const float* W_xi = (const float*)d_in[3];
    const float* W_hi = (const float*)d_in[4];
    const float* b_i  = (const float*)d_in[5];
    const float* W_xf = (const float*)d_in[6];
    const float* W_hf = (const float*)d_in[7];
    const float* b_f  = (const float*)d_in[8];
    const float* W_xo = (const float*)d_in[9];
    const float* W_ho = (const float*)d_in[10];
    const float* b_o  = (const float*)d_in[11];
    const float* W_xc = (const float*)d_in[12];
    const float* W_hc = (const float*)d_in[13];
    const float* b_c  = (const float*)d_in[14];
    const float* W_hq = (const float*)d_in[15];
    const float* b_q  = (const float*)d_in[16];

    float* out = (float*)d_out;
    char* ws = (char*)d_ws;
    unsigned* cnt  = (unsigned*)ws;
    float* fbias   = (float*)(ws + 4096);
    u16* WT        = (u16*)(ws + 20480);
    u16* Wpack     = (u16*)(ws + 18894848);
    u16* Xbf       = (u16*)(ws + 27283456);
    u16* Xp        = (u16*)(ws + 60837888);
    u16* HsBuf     = (u16*)(ws + 195055616);

    f32_to_bf16<<<16384, 256, 0, stream>>>((const float4*)inputs, (ushort4*)Xbf, 4194304);

    const float* wsrcs[9] = {W_xi, W_xf, W_xo, W_xc, W_hi, W_hf, W_ho, W_hc, W_hq};
    for (int i = 0; i < 9; ++i)
        transpose_f32_bf16<<<dim3(16, 16), 256, 0, stream>>>(wsrcs[i], WT + (size_t)i * 1048576);

    init_misc<<<256, 256, 0, stream>>>(H0, HsBuf, cnt, b_i, b_f, b_o, b_c, fbias);
    pack_wh<<<2048, 256, 0, stream>>>(WT + (size_t)4 * 1048576, Wpack);

    // fused input projection -> permuted X layout
    gemm_bt<<<dim3(128, 32), 256, 0, stream>>>(Xbf, WT, fbias, Xp, (float*)nullptr,
                                               16384, 1024, 4096, 1, 0);

    (void)hipFuncSetAttribute((const void*)lstm_steps,
                              hipFuncAttributeMaxDynamicSharedMemorySize, 163840);
    lstm_steps<<<NWG, 256, 163840, stream>>>(Xp, Wpack, C0, HsBuf, out, cnt);

    // outputs = Hs @ W_hq + b_q (fp32 out), A in Hp layout
    gemm_bt<<<dim3(128, 8), 256, 0, stream>>>(HsBuf + 65536, WT + (size_t)8 * 1048576, b_q,
                                              (u16*)nullptr, out, 16384, 1024, 1024, 0, 1);
}

// Round 7
// 2129.371 us; speedup vs baseline: 1.5287x; 1.0345x over previous
//
#include <hip/hip_runtime.h>
#include <cstdint>

typedef unsigned short u16;
typedef __attribute__((ext_vector_type(8))) short s16x8;    // 8 bf16 (4 VGPRs)
typedef __attribute__((ext_vector_type(4))) float f32x4;    // 16x16 MFMA C/D frag
typedef __attribute__((ext_vector_type(16))) float f32x16;  // 32x32 MFMA C/D frag

#define T_LEN 256
#define BATCH 64
#define HID   1024
#define NWG   64

// ---------- bf16 helpers ----------
__device__ __forceinline__ float b2f(u16 u) {
    union { unsigned u; float f; } v; v.u = ((unsigned)u) << 16; return v.f;
}
__device__ __forceinline__ u16 f2b(float f) {
    union { float f; unsigned u; } v; v.f = f;
    unsigned u = v.u;
    return (u16)((u + 0x7fffu + ((u >> 16) & 1u)) >> 16);
}
__device__ __forceinline__ float sigmoidf_(float x) { return 1.0f / (1.0f + __expf(-x)); }
__device__ __forceinline__ float tanhf_(float x) {
    float e = __expf(2.0f * x);
    return 1.0f - 2.0f / (e + 1.0f);
}

// ---------- fp32 -> bf16 bulk convert ----------
__global__ __launch_bounds__(256) void f32_to_bf16(const float4* __restrict__ in,
                                                   ushort4* __restrict__ out, int n4) {
    int i = blockIdx.x * 256 + threadIdx.x;
    if (i < n4) {
        float4 v = in[i];
        ushort4 o;
        o.x = f2b(v.x); o.y = f2b(v.y); o.z = f2b(v.z); o.w = f2b(v.w);
        out[i] = o;
    }
}

// ---------- transpose 1024x1024: out_bf16[c][r] = (bf16)in_f32[r][c] ----------
__global__ __launch_bounds__(256) void transpose_f32_bf16(const float* __restrict__ in,
                                                          u16* __restrict__ out) {
    __shared__ u16 tile[64][65];
    int tx = threadIdx.x & 63, ty = threadIdx.x >> 6;
    int r0 = blockIdx.y * 64, c0 = blockIdx.x * 64;
    for (int r = ty; r < 64; r += 4)
        tile[r][tx] = f2b(in[(size_t)(r0 + r) * 1024 + c0 + tx]);
    __syncthreads();
    for (int c = ty; c < 64; c += 4)
        out[(size_t)(c0 + c) * 1024 + r0 + tx] = tile[tx][c];
}

// ---------- init: counters, fused bias, HsBuf[0] = (bf16)H0 in Hp layout ----------
// Hp layout per step-chunk (65536 u16): off(b,k) = (k>>4)*1024 + b*16 + (k&15)
__global__ __launch_bounds__(256) void init_misc(const float* __restrict__ H0,
                                                 u16* __restrict__ HsBuf,
                                                 unsigned* __restrict__ cnt,
                                                 const float* __restrict__ b_i,
                                                 const float* __restrict__ b_f,
                                                 const float* __restrict__ b_o,
                                                 const float* __restrict__ b_c,
                                                 float* __restrict__ fbias) {
    int i = blockIdx.x * 256 + threadIdx.x;   // grid 256x256 = 65536
    if (i < 1024) cnt[i] = 0u;
    if (i < 4096) {
        int g = i >> 10, k = i & 1023;
        const float* bp = (g == 0) ? b_i : (g == 1) ? b_f : (g == 2) ? b_o : b_c;
        fbias[i] = bp[k];
    }
    if (i < BATCH * HID) {
        int b = i >> 10, k = i & 1023;
        HsBuf[(size_t)(k >> 4) * 1024 + b * 16 + (k & 15)] = f2b(H0[i]);
    }
}

// ---------- pack W_h (4 mats, [h][k] transposed layout) into MFMA-frag order ----
__global__ __launch_bounds__(256) void pack_wh(const u16* __restrict__ WThT,
                                               u16* __restrict__ Wpack) {
    size_t idx = (size_t)blockIdx.x * 256 + threadIdx.x;  // 0..524287
    int lane = idx & 63;
    int kc   = (idx >> 6) & 63;
    int ct   = (idx >> 12) & 1;
    int j    = (int)(idx >> 13);
    int ln = lane & 31, kh = lane >> 5;
    int col = ct * 32 + ln;
    int g = col >> 4, hi = col & 15;
    const uint4* src = (const uint4*)(WThT + (size_t)g * 1048576 +
                                      (size_t)(16 * j + hi) * 1024 + kc * 16 + kh * 8);
    ((uint4*)Wpack)[idx] = *src;
}

// ---------- GEMM: C[m][col] = A[m][:] . BT[col][:] + bias[col] ----------
// mode 0: Cf fp32 row-major [M][ldc].  mode 1: Cb bf16 permuted X layout (g fastest)
//   off(t,b,g,h) = t*262144 + (h>>4)*4096 + b*64 + (h&15)*4 + g, row=t*64+b, col=g*1024+h
// aperm: A is in Hp layout (per-64-row chunk of 65536 u16, off = (k>>4)*1024 + b*16 + (k&15))
__global__ __launch_bounds__(256) void gemm_bt(const u16* __restrict__ A,
                                               const u16* __restrict__ BT,
                                               const float* __restrict__ bias,
                                               u16* __restrict__ Cb,
                                               float* __restrict__ Cf,
                                               int M, int K, int ldc, int xperm, int aperm) {
    __shared__ __align__(16) u16 As[128 * 32];
    __shared__ __align__(16) u16 Bs[128 * 32];
    const int tid  = threadIdx.x;
    const int lane = tid & 63;
    const int w    = tid >> 6;
    const int wm   = (w >> 1) * 64;
    const int wn   = (w & 1) * 64;
    const long m0 = (long)blockIdx.x * 128;
    const long n0 = (long)blockIdx.y * 128;
    const int lrow = lane & 15;
    const int lq   = lane >> 4;

    f32x4 acc[4][4];
    const f32x4 vzero = {0.f, 0.f, 0.f, 0.f};
    #pragma unroll
    for (int i = 0; i < 4; ++i)
        #pragma unroll
        for (int j = 0; j < 4; ++j) acc[i][j] = vzero;

    for (int k0 = 0; k0 < K; k0 += 32) {
        __syncthreads();
        #pragma unroll
        for (int i = 0; i < 2; ++i) {
            int chunk = i * 256 + w * 64 + lane;
            const u16* ga;
            if (aperm) {
                long row = m0 + (chunk >> 2);
                int  c   = chunk & 3;
                ga = A + (row >> 6) * 65536L + (long)((k0 >> 4) + (c >> 1)) * 1024 +
                     (row & 63) * 16 + (c & 1) * 8;
            } else {
                ga = A + (m0 + (chunk >> 2)) * (long)K + k0 + (chunk & 3) * 8;
            }
            __builtin_amdgcn_global_load_lds(
                (const __attribute__((address_space(1))) unsigned int*)ga,
                (__attribute__((address_space(3))) unsigned int*)(As + (i * 256 + w * 64) * 8),
                16, 0, 0);
            const u16* gb = BT + (n0 + (chunk >> 2)) * (long)K + k0 + (chunk & 3) * 8;
            __builtin_amdgcn_global_load_lds(
                (const __attribute__((address_space(1))) unsigned int*)gb,
                (__attribute__((address_space(3))) unsigned int*)(Bs + (i * 256 + w * 64) * 8),
                16, 0, 0);
        }
        __syncthreads();
        s16x8 af[4], bf[4];
        #pragma unroll
        for (int i = 0; i < 4; ++i)
            af[i] = *(const s16x8*)(As + (wm + i * 16 + lrow) * 32 + lq * 8);
        #pragma unroll
        for (int j = 0; j < 4; ++j)
            bf[j] = *(const s16x8*)(Bs + (wn + j * 16 + lrow) * 32 + lq * 8);
        #pragma unroll
        for (int i = 0; i < 4; ++i)
            #pragma unroll
            for (int j = 0; j < 4; ++j)
                acc[i][j] = __builtin_amdgcn_mfma_f32_16x16x32_bf16(af[i], bf[j], acc[i][j], 0, 0, 0);
    }
    #pragma unroll
    for (int j = 0; j < 4; ++j) {
        long col = n0 + wn + j * 16 + lrow;
        float bv = bias[col];
        #pragma unroll
        for (int i = 0; i < 4; ++i) {
            long rowb = m0 + wm + i * 16 + lq * 4;
            #pragma unroll
            for (int r = 0; r < 4; ++r) {
                float v = acc[i][j][r] + bv;
                long row = rowb + r;
                if (xperm) {
                    long t = row >> 6, b = row & 63;
                    long g = col >> 10, h = col & 1023;
                    Cb[t * 262144 + (h >> 4) * 4096 + b * 64 + (h & 15) * 4 + g] = f2b(v);
                } else {
                    Cf[row * (long)ldc + col] = v;
                }
            }
        }
    }
}

// ---------- persistent LSTM recurrence: 64 WGs, 1 barrier/step ----------
// WG j owns cols c = g*16+hi (4 gates x 16 h), h = 16j+hi.
// K-SPLIT (round-5 proven): wave (bt,ct) computes a PARTIAL 32x64 G tile over
// k in [ct*512,(ct+1)*512), both col-tiles, zero A duplication. W in LDS.
// A-MLP FORCED (this round): 32 A-fragment loads followed by an inline-asm
// s_waitcnt vmcnt(0) with "memory" clobber -- LLVM cannot sink loads past a
// memory-clobber asm, so all 32 issue back-to-back (one round-trip for the
// 32 KB A-slice). Round 6 proved plain loads get sunk (VGPR stayed 72).
// X prefetch issued AFTER the fence so its HBM latency hides under the MFMA
// loop instead of being drained by the fence (round-4 lesson).
// Gbuf[2][64][64] partial halves, XOR-swizzled; pointwise sums the halves.
// H in Hp layout [t][k>>4][b][k&15]: A-loads wave-contiguous 1 KB, H stores
// one dwordx2/thread (512 B contiguous/wave).
// L2 warming (PROVEN x2, rounds 3/4): co-XCD WGs stream H_t slices into
// Gbuf-scratch; drained by the same A-fence (no separate vmcnt needed).
// Barrier: leaf+root two-level; busy-poll (round-6 proven).
__global__ __launch_bounds__(256, 1) void lstm_steps(const u16* __restrict__ Xp,
                                                     const u16* __restrict__ Wpack,
                                                     const float* __restrict__ C0,
                                                     u16* __restrict__ HsBuf,
                                                     float* __restrict__ out,
                                                     unsigned* __restrict__ cnt) {
    extern __shared__ char smem[];
    u16*   Wlds = (u16*)smem;                 // 131072 B, frag-packed
    float* Gbuf = (float*)(smem + 131072);    // 2*64*64*4 = 32768 B (also warm scratch)
    const int tid  = threadIdx.x;
    const int lane = tid & 63;
    const int w    = tid >> 6;
    const int j    = blockIdx.x;
    const int ln   = lane & 31;
    const int kh   = lane >> 5;
    const int bt   = w >> 1;     // row half (32 b-rows)
    const int ct   = w & 1;      // K half (512 k)

    {   // stage packed W slice (128 KB contiguous, coalesced)
        const uint4* wsrc = (const uint4*)Wpack + (size_t)j * 8192;
        uint4* wdst = (uint4*)Wlds;
        for (int i = tid; i < 8192; i += 256) wdst[i] = wsrc[i];
    }

    // pointwise mapping: thread -> (batch row pb, 4 consecutive h at 16j+hq)
    const int pb = tid >> 2;
    const int hq = (tid & 3) * 4;
    const int cg = tid & 3;        // Gbuf col group (hq>>2)
    const int pm = pb & 15;        // row swizzle key
    f32x4 c_reg = *(const f32x4*)(C0 + (size_t)pb * 1024 + 16 * j + hq);

    __syncthreads();

    unsigned* leaf = cnt + (j & 7) * 32;   // 8 leaves, 128 B apart
    unsigned* root = cnt + 512;            // separate line
    // this wave's W frag bases: chunk range [ct*32, ct*32+32) of both col-tiles
    const u16* wb0 = Wlds + (size_t)(ct * 32) * 512 + lane * 8;           // cols 0..31
    const u16* wb1 = Wlds + 32768 + (size_t)(ct * 32) * 512 + lane * 8;   // cols 32..63
    const int slice = j >> 3;              // co-XCD WGs (j%8 alike) cover 8 distinct slices

    // X for t=0 (layout: [t][j][b][(h&15)][g], g fastest) + prefetch regs
    s16x8 xlo, xhi, xnlo, xnhi;
    {
        const u16* xb0 = Xp + (size_t)j * 4096 + (size_t)pb * 64 + (size_t)hq * 4;
        xlo = *(const s16x8*)(xb0);
        xhi = *(const s16x8*)(xb0 + 8);
    }

    for (int t = 0; t < T_LEN; ++t) {
        const u16* Hbase = HsBuf + (size_t)t * 65536;

        // --- warm XCD-L2 with our 16 KB slice of H_t (fire-and-forget into scratch) ---
        #pragma unroll
        for (int i = 0; i < 4; ++i) {
            const u16* gp = Hbase + (size_t)slice * 8192 + (size_t)w * 2048 + i * 512 + lane * 8;
            __builtin_amdgcn_global_load_lds(
                (const __attribute__((address_space(1))) unsigned int*)gp,
                (__attribute__((address_space(3))) unsigned int*)
                    ((char*)Gbuf + w * 4096 + i * 1024),
                16, 0, 0);
        }

        // --- A preload: all 32 fragments issued back-to-back (MLP=32) ---
        const u16* hb2 = Hbase + (size_t)ct * 32768 + (size_t)(bt * 32 + ln) * 16 + kh * 8;
        s16x8 a[32];
        #pragma unroll
        for (int u = 0; u < 32; ++u)
            a[u] = *(const s16x8*)(hb2 + (size_t)u * 1024);
        // HARD FENCE: memory clobber pins all 32 loads above this point (no
        // sinking into the MFMA loop) and drains them + the warm DMAs.
        asm volatile("s_waitcnt vmcnt(0)" ::: "memory");

        // --- X prefetch for t+1 (post-fence: latency hides under MFMA) ---
        if (t + 1 < T_LEN) {
            const u16* xbn = Xp + (size_t)(t + 1) * 262144 + (size_t)j * 4096 +
                             (size_t)pb * 64 + (size_t)hq * 4;
            xnlo = *(const s16x8*)(xbn);
            xnhi = *(const s16x8*)(xbn + 8);
        }

        // --- MFMA (K-split): pure LDS B-reads + MFMA, A already in regs ---
        f32x16 acc0 = {};
        f32x16 acc1 = {};
        #pragma unroll
        for (int kc = 0; kc < 32; ++kc) {
            s16x8 b0 = *(const s16x8*)(wb0 + kc * 512);
            s16x8 b1 = *(const s16x8*)(wb1 + kc * 512);
            acc0 = __builtin_amdgcn_mfma_f32_32x32x16_bf16(a[kc], b0, acc0, 0, 0, 0);
            acc1 = __builtin_amdgcn_mfma_f32_32x32x16_bf16(a[kc], b1, acc1, 0, 0, 0);
        }
        // warm DMAs already drained by the A-fence; barrier orders them
        // (and Gbuf-scratch writes) across waves before G overwrites Gbuf.
        __syncthreads();
        // partial-G writes, XOR-swizzled: dword (row*64 + ((colgrp^row&15)<<2) + col&3)
        // C/D layout 32x32: col = lane&31, row = (reg&3) + 8*(reg>>2) + 4*(lane>>5)
        #pragma unroll
        for (int r = 0; r < 16; ++r) {
            int row = bt * 32 + (r & 3) + 8 * (r >> 2) + 4 * kh;
            int rm  = row & 15;
            float* gr = Gbuf + ct * 4096 + row * 64;
            gr[(((ln >> 2) ^ rm) << 2) + (ln & 3)]       = acc0[r];   // col = ln
            gr[((((ln >> 2) + 8) ^ rm) << 2) + (ln & 3)] = acc1[r];   // col = 32+ln
        }
        __syncthreads();

        // --- pointwise: sum K halves (swizzled b128 reads), dwordx2 H store ---
        const float* g0 = Gbuf + pb * 64;
        const float* g1 = Gbuf + 4096 + pb * 64;
        f32x4 gI = *(const f32x4*)(g0 + ((cg ^ pm) << 2))        + *(const f32x4*)(g1 + ((cg ^ pm) << 2));
        f32x4 gF = *(const f32x4*)(g0 + (((cg + 4) ^ pm) << 2))  + *(const f32x4*)(g1 + (((cg + 4) ^ pm) << 2));
        f32x4 gO = *(const f32x4*)(g0 + (((cg + 8) ^ pm) << 2))  + *(const f32x4*)(g1 + (((cg + 8) ^ pm) << 2));
        f32x4 gC = *(const f32x4*)(g0 + (((cg + 12) ^ pm) << 2)) + *(const f32x4*)(g1 + (((cg + 12) ^ pm) << 2));
        unsigned long long hv = 0ull;
        f32x4 hnv;
        #pragma unroll
        for (int i = 0; i < 4; ++i) {
            s16x8 xv = (i < 2) ? xlo : xhi;
            int base = (i & 1) * 4;
            float I  = sigmoidf_(gI[i] + b2f((u16)xv[base + 0]));
            float F  = sigmoidf_(gF[i] + b2f((u16)xv[base + 1]));
            float O  = sigmoidf_(gO[i] + b2f((u16)xv[base + 2]));
            float Ct = tanhf_   (gC[i] + b2f((u16)xv[base + 3]));
            float cn = F * c_reg[i] + I * Ct;
            c_reg[i] = cn;
            float hn = O * tanhf_(cn);
            hnv[i] = hn;
            hv |= (unsigned long long)f2b(hn) << (16 * i);
        }

        // --- write-through H store: 8 B/thread, 512 B contiguous per wave ---
        u16* dst = HsBuf + (size_t)(t + 1) * 65536 + (size_t)j * 1024 + pb * 16 + hq;
        asm volatile("global_store_dwordx2 %0, %1, off sc0 sc1"
                     :: "v"(dst), "v"(hv) : "memory");

        if (t == T_LEN - 1) {
            *(float4*)(out + 16777216 + (size_t)pb * 1024 + 16 * j + hq) = *(float4*)&hnv;           // Hf
            *(float4*)(out + 16777216 + 65536 + (size_t)pb * 1024 + 16 * j + hq) = *(float4*)&c_reg; // Cf
            break;
        }

        // rotate X prefetch regs (reg-only, overlaps drain)
        xlo = xnlo; xhi = xnhi;

        // release: drain H store, sync waves, then two-level device barrier
        asm volatile("s_waitcnt vmcnt(0)" ::: "memory");
        __syncthreads();
        if (tid == 0) {
            unsigned old = __hip_atomic_fetch_add(leaf, 1u, __ATOMIC_RELAXED,
                                                  __HIP_MEMORY_SCOPE_AGENT);
            if (old == 8u * (unsigned)t + 7u)
                __hip_atomic_fetch_add(root, 1u, __ATOMIC_RELAXED, __HIP_MEMORY_SCOPE_AGENT);
            unsigned tgt = 8u * (unsigned)(t + 1);
            while (__hip_atomic_load(root, __ATOMIC_RELAXED, __HIP_MEMORY_SCOPE_AGENT) < tgt) {}
        }
        __syncthreads();
    }
}

// ---------- workspace layout (bytes) ----------
//   0         : cnt[1024] (leaves at dword (j&7)*32, root at dword 512)   4096 B
//   4096      : fused bias f32[4096]                                     16384 B
//   20480     : 9 transposed bf16 weights, 2 MB each (Wxi..Wxc, Whi..Whc, Whq)
//   18894848  : Wpack bf16, MFMA-frag order                            8388608 B
//   27283456  : Xbf  bf16 [16384][1024]                               33554432 B
//   60837888  : Xp   bf16 permuted [t][h>>4][b][h&15][g]             134217728 B
//   195055616 : HsBuf bf16 [257] chunks, Hp layout [k>>4][b][k&15]    33685504 B
extern "C" void kernel_launch(void* const* d_in, const int* in_sizes, int n_in,
                              void* d_out, int out_size, void* d_ws, size_t ws_size,
                              hipStream_t stream) {
    const float* inputs = (const float*)d_in[0];
    const float* H0   = (const float*)d_in[1];
    const float* C0   = (const float*)d_in[2];
    const float* W_xi = (const float*)d_in[3];
    const float* W_hi = (const float*)d_in[4];
    const float* b_i  = (const float*)d_in[5];
    const float* W_xf = (const float*)d_in[6];
    const float* W_hf = (const float*)d_in[7];
    const float* b_f  = (const float*)d_in[8];
    const float* W_xo = (const float*)d_in[9];
    const float* W_ho = (const float*)d_in[10];
    const float* b_o  = (const float*)d_in[11];
    const float* W_xc = (const float*)d_in[12];
    const float* W_hc = (const float*)d_in[13];
    const float* b_c  = (const float*)d_in[14];
    const float* W_hq = (const float*)d_in[15];
    const float* b_q  = (const float*)d_in[16];

    float* out = (float*)d_out;
    char* ws = (char*)d_ws;
    unsigned* cnt  = (unsigned*)ws;
    float* fbias   = (float*)(ws + 4096);
    u16* WT        = (u16*)(ws + 20480);
    u16* Wpack     = (u16*)(ws + 18894848);
    u16* Xbf       = (u16*)(ws + 27283456);
    u16* Xp        = (u16*)(ws + 60837888);
    u16* HsBuf     = (u16*)(ws + 195055616);

    f32_to_bf16<<<16384, 256, 0, stream>>>((const float4*)inputs, (ushort4*)Xbf, 4194304);

    const float* wsrcs[9] = {W_xi, W_xf, W_xo, W_xc, W_hi, W_hf, W_ho, W_hc, W_hq};
    for (int i = 0; i < 9; ++i)
        transpose_f32_bf16<<<dim3(16, 16), 256, 0, stream>>>(wsrcs[i], WT + (size_t)i * 1048576);

    init_misc<<<256, 256, 0, stream>>>(H0, HsBuf, cnt, b_i, b_f, b_o, b_c, fbias);
    pack_wh<<<2048, 256, 0, stream>>>(WT + (size_t)4 * 1048576, Wpack);

    // fused input projection -> permuted X layout
    gemm_bt<<<dim3(128, 32), 256, 0, stream>>>(Xbf, WT, fbias, Xp, (float*)nullptr,
                                               16384, 1024, 4096, 1, 0);

    (void)hipFuncSetAttribute((const void*)lstm_steps,
                              hipFuncAttributeMaxDynamicSharedMemorySize, 163840);
    lstm_steps<<<NWG, 256, 163840, stream>>>(Xp, Wpack, C0, HsBuf, out, cnt);

    // outputs = Hs @ W_hq + b_q (fp32 out), A in Hp layout
    gemm_bt<<<dim3(128, 8), 256, 0, stream>>>(HsBuf + 65536, WT + (size_t)8 * 1048576, b_q,
                                              (u16*)nullptr, out, 16384, 1024, 1024, 0, 1);
}

// Round 8
// 1843.410 us; speedup vs baseline: 1.7659x; 1.1551x over previous
//
#include <hip/hip_runtime.h>
#include <cstdint>

typedef unsigned short u16;
typedef __attribute__((ext_vector_type(8))) short s16x8;    // 8 bf16 (4 VGPRs)
typedef __attribute__((ext_vector_type(4))) float f32x4;    // 16x16 MFMA C/D frag
typedef __attribute__((ext_vector_type(16))) float f32x16;  // 32x32 MFMA C/D frag

#define T_LEN 256
#define BATCH 64
#define HID   1024
#define NWG   64

// ---------- bf16 helpers ----------
__device__ __forceinline__ float b2f(u16 u) {
    union { unsigned u; float f; } v; v.u = ((unsigned)u) << 16; return v.f;
}
__device__ __forceinline__ u16 f2b(float f) {
    union { float f; unsigned u; } v; v.f = f;
    unsigned u = v.u;
    return (u16)((u + 0x7fffu + ((u >> 16) & 1u)) >> 16);
}
__device__ __forceinline__ float sigmoidf_(float x) { return 1.0f / (1.0f + __expf(-x)); }
__device__ __forceinline__ float tanhf_(float x) {
    float e = __expf(2.0f * x);
    return 1.0f - 2.0f / (e + 1.0f);
}

// ---------- fp32 -> bf16 bulk convert ----------
__global__ __launch_bounds__(256) void f32_to_bf16(const float4* __restrict__ in,
                                                   ushort4* __restrict__ out, int n4) {
    int i = blockIdx.x * 256 + threadIdx.x;
    if (i < n4) {
        float4 v = in[i];
        ushort4 o;
        o.x = f2b(v.x); o.y = f2b(v.y); o.z = f2b(v.z); o.w = f2b(v.w);
        out[i] = o;
    }
}

// ---------- transpose 1024x1024: out_bf16[c][r] = (bf16)in_f32[r][c] ----------
__global__ __launch_bounds__(256) void transpose_f32_bf16(const float* __restrict__ in,
                                                          u16* __restrict__ out) {
    __shared__ u16 tile[64][65];
    int tx = threadIdx.x & 63, ty = threadIdx.x >> 6;
    int r0 = blockIdx.y * 64, c0 = blockIdx.x * 64;
    for (int r = ty; r < 64; r += 4)
        tile[r][tx] = f2b(in[(size_t)(r0 + r) * 1024 + c0 + tx]);
    __syncthreads();
    for (int c = ty; c < 64; c += 4)
        out[(size_t)(c0 + c) * 1024 + r0 + tx] = tile[tx][c];
}

// ---------- init: counters, fused bias, HsBuf[0] = (bf16)H0 in Hp layout ----------
// Hp layout per step-chunk (65536 u16): off(b,k) = (k>>4)*1024 + b*16 + (k&15)
__global__ __launch_bounds__(256) void init_misc(const float* __restrict__ H0,
                                                 u16* __restrict__ HsBuf,
                                                 unsigned* __restrict__ cnt,
                                                 const float* __restrict__ b_i,
                                                 const float* __restrict__ b_f,
                                                 const float* __restrict__ b_o,
                                                 const float* __restrict__ b_c,
                                                 float* __restrict__ fbias) {
    int i = blockIdx.x * 256 + threadIdx.x;   // grid 256x256 = 65536
    if (i < 1024) cnt[i] = 0u;
    if (i < 4096) {
        int g = i >> 10, k = i & 1023;
        const float* bp = (g == 0) ? b_i : (g == 1) ? b_f : (g == 2) ? b_o : b_c;
        fbias[i] = bp[k];
    }
    if (i < BATCH * HID) {
        int b = i >> 10, k = i & 1023;
        HsBuf[(size_t)(k >> 4) * 1024 + b * 16 + (k & 15)] = f2b(H0[i]);
    }
}

// ---------- pack W_h (4 mats, [h][k] transposed layout) into MFMA-frag order ----
__global__ __launch_bounds__(256) void pack_wh(const u16* __restrict__ WThT,
                                               u16* __restrict__ Wpack) {
    size_t idx = (size_t)blockIdx.x * 256 + threadIdx.x;  // 0..524287
    int lane = idx & 63;
    int kc   = (idx >> 6) & 63;
    int ct   = (idx >> 12) & 1;
    int j    = (int)(idx >> 13);
    int ln = lane & 31, kh = lane >> 5;
    int col = ct * 32 + ln;
    int g = col >> 4, hi = col & 15;
    const uint4* src = (const uint4*)(WThT + (size_t)g * 1048576 +
                                      (size_t)(16 * j + hi) * 1024 + kc * 16 + kh * 8);
    ((uint4*)Wpack)[idx] = *src;
}

// ---------- GEMM: C[m][col] = A[m][:] . BT[col][:] + bias[col] ----------
// mode 0: Cf fp32 row-major [M][ldc].  mode 1: Cb bf16 permuted X layout (g fastest)
//   off(t,b,g,h) = t*262144 + (h>>4)*4096 + b*64 + (h&15)*4 + g, row=t*64+b, col=g*1024+h
// aperm: A is in Hp layout (per-64-row chunk of 65536 u16, off = (k>>4)*1024 + b*16 + (k&15))
__global__ __launch_bounds__(256) void gemm_bt(const u16* __restrict__ A,
                                               const u16* __restrict__ BT,
                                               const float* __restrict__ bias,
                                               u16* __restrict__ Cb,
                                               float* __restrict__ Cf,
                                               int M, int K, int ldc, int xperm, int aperm) {
    __shared__ __align__(16) u16 As[128 * 32];
    __shared__ __align__(16) u16 Bs[128 * 32];
    const int tid  = threadIdx.x;
    const int lane = tid & 63;
    const int w    = tid >> 6;
    const int wm   = (w >> 1) * 64;
    const int wn   = (w & 1) * 64;
    const long m0 = (long)blockIdx.x * 128;
    const long n0 = (long)blockIdx.y * 128;
    const int lrow = lane & 15;
    const int lq   = lane >> 4;

    f32x4 acc[4][4];
    const f32x4 vzero = {0.f, 0.f, 0.f, 0.f};
    #pragma unroll
    for (int i = 0; i < 4; ++i)
        #pragma unroll
        for (int j = 0; j < 4; ++j) acc[i][j] = vzero;

    for (int k0 = 0; k0 < K; k0 += 32) {
        __syncthreads();
        #pragma unroll
        for (int i = 0; i < 2; ++i) {
            int chunk = i * 256 + w * 64 + lane;
            const u16* ga;
            if (aperm) {
                long row = m0 + (chunk >> 2);
                int  c   = chunk & 3;
                ga = A + (row >> 6) * 65536L + (long)((k0 >> 4) + (c >> 1)) * 1024 +
                     (row & 63) * 16 + (c & 1) * 8;
            } else {
                ga = A + (m0 + (chunk >> 2)) * (long)K + k0 + (chunk & 3) * 8;
            }
            __builtin_amdgcn_global_load_lds(
                (const __attribute__((address_space(1))) unsigned int*)ga,
                (__attribute__((address_space(3))) unsigned int*)(As + (i * 256 + w * 64) * 8),
                16, 0, 0);
            const u16* gb = BT + (n0 + (chunk >> 2)) * (long)K + k0 + (chunk & 3) * 8;
            __builtin_amdgcn_global_load_lds(
                (const __attribute__((address_space(1))) unsigned int*)gb,
                (__attribute__((address_space(3))) unsigned int*)(Bs + (i * 256 + w * 64) * 8),
                16, 0, 0);
        }
        __syncthreads();
        s16x8 af[4], bf[4];
        #pragma unroll
        for (int i = 0; i < 4; ++i)
            af[i] = *(const s16x8*)(As + (wm + i * 16 + lrow) * 32 + lq * 8);
        #pragma unroll
        for (int j = 0; j < 4; ++j)
            bf[j] = *(const s16x8*)(Bs + (wn + j * 16 + lrow) * 32 + lq * 8);
        #pragma unroll
        for (int i = 0; i < 4; ++i)
            #pragma unroll
            for (int j = 0; j < 4; ++j)
                acc[i][j] = __builtin_amdgcn_mfma_f32_16x16x32_bf16(af[i], bf[j], acc[i][j], 0, 0, 0);
    }
    #pragma unroll
    for (int j = 0; j < 4; ++j) {
        long col = n0 + wn + j * 16 + lrow;
        float bv = bias[col];
        #pragma unroll
        for (int i = 0; i < 4; ++i) {
            long rowb = m0 + wm + i * 16 + lq * 4;
            #pragma unroll
            for (int r = 0; r < 4; ++r) {
                float v = acc[i][j][r] + bv;
                long row = rowb + r;
                if (xperm) {
                    long t = row >> 6, b = row & 63;
                    long g = col >> 10, h = col & 1023;
                    Cb[t * 262144 + (h >> 4) * 4096 + b * 64 + (h & 15) * 4 + g] = f2b(v);
                } else {
                    Cf[row * (long)ldc + col] = v;
                }
            }
        }
    }
}

// ---------- persistent LSTM recurrence: 64 WGs, 1 barrier/step ----------
// WG j owns cols c = g*16+hi (4 gates x 16 h), h = 16j+hi.
// K-SPLIT (round-5 proven): wave (bt,ct) computes a PARTIAL 32x64 G tile over
// k in [ct*512,(ct+1)*512), both col-tiles, zero A duplication. W in LDS.
// A-MLP FORCED (round-7 proven, VGPR 72->128): 32 A-fragment loads + inline-asm
// s_waitcnt vmcnt(0) memory-clobber fence -- all 32 issue back-to-back, one
// MALL round-trip for the 32 KB A-slice.
// WARMING REMOVED (this round): its proven role (rounds 3/4) was decoupling
// MALL RTs from the serialized MLP~4 A-chain; with forced MLP=32 all A-loads
// are already in flight in parallel -- warming is pure overhead now. Its
// removal also kills the Gbuf-scratch hazard, so the post-MFMA first
// __syncthreads() is deleted too (prev-step Gbuf reads are ordered by the
// two barrier-side syncthreads).
// BARRIER SHORTENED (this round): no root hop. tid0 adds its leaf; wave-0
// lanes poll all 8 leaves directly (lane&7). Chain = drain -> leaf RMW ->
// detect (one MALL RT shorter than leaf->root->detect). Busy-poll (round-6).
// X prefetch post-fence (round-7). H in Hp layout [t][k>>4][b][k&15]:
// A-loads wave-contiguous 1 KB, H stores one dwordx2/thread (512 B/wave).
// Write-through H stores (sc0 sc1).
__global__ __launch_bounds__(256, 1) void lstm_steps(const u16* __restrict__ Xp,
                                                     const u16* __restrict__ Wpack,
                                                     const float* __restrict__ C0,
                                                     u16* __restrict__ HsBuf,
                                                     float* __restrict__ out,
                                                     unsigned* __restrict__ cnt) {
    extern __shared__ char smem[];
    u16*   Wlds = (u16*)smem;                 // 131072 B, frag-packed
    float* Gbuf = (float*)(smem + 131072);    // 2*64*64*4 = 32768 B
    const int tid  = threadIdx.x;
    const int lane = tid & 63;
    const int w    = tid >> 6;
    const int j    = blockIdx.x;
    const int ln   = lane & 31;
    const int kh   = lane >> 5;
    const int bt   = w >> 1;     // row half (32 b-rows)
    const int ct   = w & 1;      // K half (512 k)

    {   // stage packed W slice (128 KB contiguous, coalesced)
        const uint4* wsrc = (const uint4*)Wpack + (size_t)j * 8192;
        uint4* wdst = (uint4*)Wlds;
        for (int i = tid; i < 8192; i += 256) wdst[i] = wsrc[i];
    }

    // pointwise mapping: thread -> (batch row pb, 4 consecutive h at 16j+hq)
    const int pb = tid >> 2;
    const int hq = (tid & 3) * 4;
    const int cg = tid & 3;        // Gbuf col group (hq>>2)
    const int pm = pb & 15;        // row swizzle key
    f32x4 c_reg = *(const f32x4*)(C0 + (size_t)pb * 1024 + 16 * j + hq);

    __syncthreads();

    unsigned* leaf = cnt + (j & 7) * 32;   // 8 leaves, 128 B apart
    // this wave's W frag bases: chunk range [ct*32, ct*32+32) of both col-tiles
    const u16* wb0 = Wlds + (size_t)(ct * 32) * 512 + lane * 8;           // cols 0..31
    const u16* wb1 = Wlds + 32768 + (size_t)(ct * 32) * 512 + lane * 8;   // cols 32..63

    // X for t=0 (layout: [t][j][b][(h&15)][g], g fastest) + prefetch regs
    s16x8 xlo, xhi, xnlo, xnhi;
    {
        const u16* xb0 = Xp + (size_t)j * 4096 + (size_t)pb * 64 + (size_t)hq * 4;
        xlo = *(const s16x8*)(xb0);
        xhi = *(const s16x8*)(xb0 + 8);
    }

    for (int t = 0; t < T_LEN; ++t) {
        const u16* Hbase = HsBuf + (size_t)t * 65536;

        // --- A preload: all 32 fragments issued back-to-back (MLP=32) ---
        const u16* hb2 = Hbase + (size_t)ct * 32768 + (size_t)(bt * 32 + ln) * 16 + kh * 8;
        s16x8 a[32];
        #pragma unroll
        for (int u = 0; u < 32; ++u)
            a[u] = *(const s16x8*)(hb2 + (size_t)u * 1024);
        // HARD FENCE: memory clobber pins all 32 loads above this point (no
        // sinking into the MFMA loop) and drains them.
        asm volatile("s_waitcnt vmcnt(0)" ::: "memory");

        // --- X prefetch for t+1 (post-fence: latency hides under MFMA) ---
        if (t + 1 < T_LEN) {
            const u16* xbn = Xp + (size_t)(t + 1) * 262144 + (size_t)j * 4096 +
                             (size_t)pb * 64 + (size_t)hq * 4;
            xnlo = *(const s16x8*)(xbn);
            xnhi = *(const s16x8*)(xbn + 8);
        }

        // --- MFMA (K-split): pure LDS B-reads + MFMA, A already in regs ---
        f32x16 acc0 = {};
        f32x16 acc1 = {};
        #pragma unroll
        for (int kc = 0; kc < 32; ++kc) {
            s16x8 b0 = *(const s16x8*)(wb0 + kc * 512);
            s16x8 b1 = *(const s16x8*)(wb1 + kc * 512);
            acc0 = __builtin_amdgcn_mfma_f32_32x32x16_bf16(a[kc], b0, acc0, 0, 0, 0);
            acc1 = __builtin_amdgcn_mfma_f32_32x32x16_bf16(a[kc], b1, acc1, 0, 0, 0);
        }
        // partial-G writes straight after MFMA (per-wave disjoint rows/planes;
        // prev-step Gbuf reads already ordered by the barrier syncthreads).
        // XOR-swizzled: dword (row*64 + ((colgrp^row&15)<<2) + col&3)
        // C/D layout 32x32: col = lane&31, row = (reg&3) + 8*(reg>>2) + 4*(lane>>5)
        #pragma unroll
        for (int r = 0; r < 16; ++r) {
            int row = bt * 32 + (r & 3) + 8 * (r >> 2) + 4 * kh;
            int rm  = row & 15;
            float* gr = Gbuf + ct * 4096 + row * 64;
            gr[(((ln >> 2) ^ rm) << 2) + (ln & 3)]       = acc0[r];   // col = ln
            gr[((((ln >> 2) + 8) ^ rm) << 2) + (ln & 3)] = acc1[r];   // col = 32+ln
        }
        __syncthreads();

        // --- pointwise: sum K halves (swizzled b128 reads), dwordx2 H store ---
        const float* g0 = Gbuf + pb * 64;
        const float* g1 = Gbuf + 4096 + pb * 64;
        f32x4 gI = *(const f32x4*)(g0 + ((cg ^ pm) << 2))        + *(const f32x4*)(g1 + ((cg ^ pm) << 2));
        f32x4 gF = *(const f32x4*)(g0 + (((cg + 4) ^ pm) << 2))  + *(const f32x4*)(g1 + (((cg + 4) ^ pm) << 2));
        f32x4 gO = *(const f32x4*)(g0 + (((cg + 8) ^ pm) << 2))  + *(const f32x4*)(g1 + (((cg + 8) ^ pm) << 2));
        f32x4 gC = *(const f32x4*)(g0 + (((cg + 12) ^ pm) << 2)) + *(const f32x4*)(g1 + (((cg + 12) ^ pm) << 2));
        unsigned long long hv = 0ull;
        f32x4 hnv;
        #pragma unroll
        for (int i = 0; i < 4; ++i) {
            s16x8 xv = (i < 2) ? xlo : xhi;
            int base = (i & 1) * 4;
            float I  = sigmoidf_(gI[i] + b2f((u16)xv[base + 0]));
            float F  = sigmoidf_(gF[i] + b2f((u16)xv[base + 1]));
            float O  = sigmoidf_(gO[i] + b2f((u16)xv[base + 2]));
            float Ct = tanhf_   (gC[i] + b2f((u16)xv[base + 3]));
            float cn = F * c_reg[i] + I * Ct;
            c_reg[i] = cn;
            float hn = O * tanhf_(cn);
            hnv[i] = hn;
            hv |= (unsigned long long)f2b(hn) << (16 * i);
        }

        // --- write-through H store: 8 B/thread, 512 B contiguous per wave ---
        u16* dst = HsBuf + (size_t)(t + 1) * 65536 + (size_t)j * 1024 + pb * 16 + hq;
        asm volatile("global_store_dwordx2 %0, %1, off sc0 sc1"
                     :: "v"(dst), "v"(hv) : "memory");

        if (t == T_LEN - 1) {
            *(float4*)(out + 16777216 + (size_t)pb * 1024 + 16 * j + hq) = *(float4*)&hnv;           // Hf
            *(float4*)(out + 16777216 + 65536 + (size_t)pb * 1024 + 16 * j + hq) = *(float4*)&c_reg; // Cf
            break;
        }

        // rotate X prefetch regs (reg-only, overlaps drain)
        xlo = xnlo; xhi = xnhi;

        // release: drain H store, sync waves, leaf add; acquire: poll 8 leaves
        asm volatile("s_waitcnt vmcnt(0)" ::: "memory");
        __syncthreads();
        if (tid == 0)
            __hip_atomic_fetch_add(leaf, 1u, __ATOMIC_RELAXED, __HIP_MEMORY_SCOPE_AGENT);
        if (w == 0) {
            unsigned tgt = 8u * (unsigned)(t + 1);
            const unsigned* lp = cnt + (lane & 7) * 32;
            while (__hip_atomic_load(lp, __ATOMIC_RELAXED, __HIP_MEMORY_SCOPE_AGENT) < tgt) {}
        }
        __syncthreads();
    }
}

// ---------- workspace layout (bytes) ----------
//   0         : cnt[1024] (8 leaves at dword (j&7)*32)                    4096 B
//   4096      : fused bias f32[4096]                                     16384 B
//   20480     : 9 transposed bf16 weights, 2 MB each (Wxi..Wxc, Whi..Whc, Whq)
//   18894848  : Wpack bf16, MFMA-frag order                            8388608 B
//   27283456  : Xbf  bf16 [16384][1024]                               33554432 B
//   60837888  : Xp   bf16 permuted [t][h>>4][b][h&15][g]             134217728 B
//   195055616 : HsBuf bf16 [257] chunks, Hp layout [k>>4][b][k&15]    33685504 B
extern "C" void kernel_launch(void* const* d_in, const int* in_sizes, int n_in,
                              void* d_out, int out_size, void* d_ws, size_t ws_size,
                              hipStream_t stream) {
    const float* inputs = (const float*)d_in[0];
    const float* H0   = (const float*)d_in[1];
    const float* C0   = (const float*)d_in[2];
    const float* W_xi = (const float*)d_in[3];
    const float* W_hi = (const float*)d_in[4];
    const float* b_i  = (const float*)d_in[5];
    const float* W_xf = (const float*)d_in[6];
    const float* W_hf = (const float*)d_in[7];
    const float* b_f  = (const float*)d_in[8];
    const float* W_xo = (const float*)d_in[9];
    const float* W_ho = (const float*)d_in[10];
    const float* b_o  = (const float*)d_in[11];
    const float* W_xc = (const float*)d_in[12];
    const float* W_hc = (const float*)d_in[13];
    const float* b_c  = (const float*)d_in[14];
    const float* W_hq = (const float*)d_in[15];
    const float* b_q  = (const float*)d_in[16];

    float* out = (float*)d_out;
    char* ws = (char*)d_ws;
    unsigned* cnt  = (unsigned*)ws;
    float* fbias   = (float*)(ws + 4096);
    u16* WT        = (u16*)(ws + 20480);
    u16* Wpack     = (u16*)(ws + 18894848);
    u16* Xbf       = (u16*)(ws + 27283456);
    u16* Xp        = (u16*)(ws + 60837888);
    u16* HsBuf     = (u16*)(ws + 195055616);

    f32_to_bf16<<<16384, 256, 0, stream>>>((const float4*)inputs, (ushort4*)Xbf, 4194304);

    const float* wsrcs[9] = {W_xi, W_xf, W_xo, W_xc, W_hi, W_hf, W_ho, W_hc, W_hq};
    for (int i = 0; i < 9; ++i)
        transpose_f32_bf16<<<dim3(16, 16), 256, 0, stream>>>(wsrcs[i], WT + (size_t)i * 1048576);

    init_misc<<<256, 256, 0, stream>>>(H0, HsBuf, cnt, b_i, b_f, b_o, b_c, fbias);
    pack_wh<<<2048, 256, 0, stream>>>(WT + (size_t)4 * 1048576, Wpack);

    // fused input projection -> permuted X layout
    gemm_bt<<<dim3(128, 32), 256, 0, stream>>>(Xbf, WT, fbias, Xp, (float*)nullptr,
                                               16384, 1024, 4096, 1, 0);

    (void)hipFuncSetAttribute((const void*)lstm_steps,
                              hipFuncAttributeMaxDynamicSharedMemorySize, 163840);
    lstm_steps<<<NWG, 256, 163840, stream>>>(Xp, Wpack, C0, HsBuf, out, cnt);

    // outputs = Hs @ W_hq + b_q (fp32 out), A in Hp layout
    gemm_bt<<<dim3(128, 8), 256, 0, stream>>>(HsBuf + 65536, WT + (size_t)8 * 1048576, b_q,
                                              (u16*)nullptr, out, 16384, 1024, 1024, 0, 1);
}